// Round 1
// baseline (7144.620 us; speedup 1.0000x reference)
//
#include <hip/hip_runtime.h>
#include <math.h>

#define DMODEL 256
#define HEADS 8
#define DHEAD 32
#define LEVELS 4
#define POINTS 4
#define NLAYERS 6
#define DFF 1024
#define BS 4
#define NQ 900
#define SLEN 19560
#define EPS_LN 1e-5f
#define ATT_SCALE 0.17677669529663689f

// ---------------------------------------------------------------- elementwise
__global__ __launch_bounds__(256) void add_k(const float* __restrict__ a,
                                             const float* __restrict__ b,
                                             float* __restrict__ c, int n4) {
  int i = blockIdx.x * 256 + threadIdx.x;
  if (i < n4) {
    float4 av = reinterpret_cast<const float4*>(a)[i];
    float4 bv = reinterpret_cast<const float4*>(b)[i];
    float4 cv = {av.x + bv.x, av.y + bv.y, av.z + bv.z, av.w + bv.w};
    reinterpret_cast<float4*>(c)[i] = cv;
  }
}

__global__ __launch_bounds__(256) void copy_k(const float* __restrict__ a,
                                              float* __restrict__ c, int n4) {
  int i = blockIdx.x * 256 + threadIdx.x;
  if (i < n4) reinterpret_cast<float4*>(c)[i] = reinterpret_cast<const float4*>(a)[i];
}

// ---------------------------------------------------------------- GEMM
// C[M,N] = A[M,K] @ W[N,K]^T + bias[N] (+ res[M,N]) (+ relu)
__global__ __launch_bounds__(256) void gemm_k(const float* __restrict__ A,
                                              const float* __restrict__ W,
                                              const float* __restrict__ bias,
                                              const float* __restrict__ res,
                                              float* __restrict__ C,
                                              int M, int N, int K, int relu) {
  __shared__ float As[64][17];
  __shared__ float Bs[16][65];
  const int tid = threadIdx.x;
  const int tr = tid >> 4, tc = tid & 15;
  const int bm = blockIdx.x, bn = blockIdx.y;
  const int arow = tid >> 2;          // 0..63
  const int acol = (tid & 3) << 2;    // 0,4,8,12
  const int grow = bm * 64 + arow;
  const bool aval = grow < M;
  const int wrow = bn * 64 + arow;    // N is multiple of 64

  float acc[4][4] = {};
  for (int k0 = 0; k0 < K; k0 += 16) {
    float4 av = aval ? *reinterpret_cast<const float4*>(A + (size_t)grow * K + k0 + acol)
                     : float4{0.f, 0.f, 0.f, 0.f};
    float4 wv = *reinterpret_cast<const float4*>(W + (size_t)wrow * K + k0 + acol);
    As[arow][acol + 0] = av.x; As[arow][acol + 1] = av.y;
    As[arow][acol + 2] = av.z; As[arow][acol + 3] = av.w;
    Bs[acol + 0][arow] = wv.x; Bs[acol + 1][arow] = wv.y;
    Bs[acol + 2][arow] = wv.z; Bs[acol + 3][arow] = wv.w;
    __syncthreads();
#pragma unroll
    for (int kk = 0; kk < 16; ++kk) {
      float a[4], b[4];
#pragma unroll
      for (int i = 0; i < 4; ++i) a[i] = As[tr * 4 + i][kk];
#pragma unroll
      for (int j = 0; j < 4; ++j) b[j] = Bs[kk][tc * 4 + j];
#pragma unroll
      for (int i = 0; i < 4; ++i)
#pragma unroll
        for (int j = 0; j < 4; ++j) acc[i][j] = fmaf(a[i], b[j], acc[i][j]);
    }
    __syncthreads();
  }
#pragma unroll
  for (int i = 0; i < 4; ++i) {
    int m = bm * 64 + tr * 4 + i;
    if (m >= M) continue;
#pragma unroll
    for (int j = 0; j < 4; ++j) {
      int n = bn * 64 + tc * 4 + j;
      float v = acc[i][j] + bias[n];
      if (res) v += res[(size_t)m * N + n];
      if (relu) v = fmaxf(v, 0.f);
      C[(size_t)m * N + n] = v;
    }
  }
}

// ---------------------------------------------------------------- self-attn
// One block per (qi, h, b). qh/kh/vh are (B,NQ,256) with col = h*32+d.
__global__ __launch_bounds__(256) void attn_k(const float* __restrict__ qh,
                                              const float* __restrict__ kh,
                                              const float* __restrict__ vh,
                                              float* __restrict__ o) {
  const int qi = blockIdx.x, h = blockIdx.y, b = blockIdx.z;
  __shared__ float qrow[32];
  __shared__ float s[NQ];
  __shared__ float red[256];
  __shared__ float part[8][33];
  const int tid = threadIdx.x;
  const float* qptr = qh + ((size_t)(b * NQ + qi) * DMODEL + h * DHEAD);
  if (tid < 32) qrow[tid] = qptr[tid];
  __syncthreads();

  float lmax = -1e30f;
  for (int k = tid; k < NQ; k += 256) {
    const float* kptr = kh + ((size_t)(b * NQ + k) * DMODEL + h * DHEAD);
    float acc = 0.f;
#pragma unroll
    for (int d2 = 0; d2 < 32; ++d2) acc = fmaf(qrow[d2], kptr[d2], acc);
    acc *= ATT_SCALE;
    s[k] = acc;
    lmax = fmaxf(lmax, acc);
  }
  red[tid] = lmax;
  __syncthreads();
  for (int off = 128; off > 0; off >>= 1) {
    if (tid < off) red[tid] = fmaxf(red[tid], red[tid + off]);
    __syncthreads();
  }
  const float mx = red[0];
  __syncthreads();

  float lsum = 0.f;
  for (int k = tid; k < NQ; k += 256) {
    float p = expf(s[k] - mx);
    s[k] = p;
    lsum += p;
  }
  red[tid] = lsum;
  __syncthreads();
  for (int off = 128; off > 0; off >>= 1) {
    if (tid < off) red[tid] += red[tid + off];
    __syncthreads();
  }
  const float denom = red[0];
  __syncthreads();

  const int d = tid & 31, c = tid >> 5;
  float acc = 0.f;
  for (int k = c; k < NQ; k += 8)
    acc = fmaf(s[k], vh[(size_t)(b * NQ + k) * DMODEL + h * DHEAD + d], acc);
  part[c][d] = acc;
  __syncthreads();
  if (tid < 32) {
    float t = 0.f;
#pragma unroll
    for (int cc = 0; cc < 8; ++cc) t += part[cc][tid];
    o[(size_t)(b * NQ + qi) * DMODEL + h * DHEAD + tid] = t / denom;
  }
}

// ---------------------------------------------------------------- MSDA sample
// One block (256 thr) per (qi, b); tid = h*32 + d.
__global__ __launch_bounds__(256) void msda_k(const float* __restrict__ refp,   // (B,NQ,3)
                                              const float* __restrict__ vr,     // (B,LEVELS,2)
                                              const float* __restrict__ value,  // (B,SLEN,256)
                                              const float* __restrict__ offb,   // (B,NQ,256)
                                              const float* __restrict__ attl,   // (B,NQ,128)
                                              float* __restrict__ outp) {       // (B,NQ,256)
  const int HW[4][2] = {{92, 160}, {46, 80}, {23, 40}, {12, 20}};
  const int START[4] = {0, 14720, 18400, 19320};
  const int qi = blockIdx.x, b = blockIdx.y;
  const int tid = threadIdx.x;
  const int h = tid >> 5, d = tid & 31;
  const size_t base = (size_t)(b * NQ + qi);
  const float rx = refp[base * 3 + 0];
  const float rz = refp[base * 3 + 2];

  // softmax over 16 logits for this head (computed redundantly in 32-lane group)
  const float* lg = attl + base * 128 + h * 16;
  float lv[16];
  float mx = -1e30f;
#pragma unroll
  for (int j = 0; j < 16; ++j) { lv[j] = lg[j]; mx = fmaxf(mx, lv[j]); }
  float sum = 0.f;
#pragma unroll
  for (int j = 0; j < 16; ++j) { lv[j] = expf(lv[j] - mx); sum += lv[j]; }
  const float inv = 1.f / sum;

  const float* ob = offb + base * 256 + h * 32;
  float acc = 0.f;
#pragma unroll
  for (int l = 0; l < 4; ++l) {
    const int H = HW[l][0], W = HW[l][1];
    const float refx = rx * vr[(b * LEVELS + l) * 2 + 0];
    const float refy = rz * vr[(b * LEVELS + l) * 2 + 1];
    const float* vbase = value + ((size_t)b * SLEN + START[l]) * DMODEL + h * DHEAD + d;
#pragma unroll
    for (int p = 0; p < 4; ++p) {
      const float offx = ob[l * 8 + p * 2 + 0];
      const float offy = ob[l * 8 + p * 2 + 1];
      const float x = (refx + offx / (float)W) * (float)W - 0.5f;
      const float y = (refy + offy / (float)H) * (float)H - 0.5f;
      const float x0f = floorf(x), y0f = floorf(y);
      const float fx = x - x0f, fy = y - y0f;
      const int x0 = (int)x0f, y0 = (int)y0f;
      float sv = 0.f;
#pragma unroll
      for (int ci = 0; ci < 4; ++ci) {
        const int xi = x0 + (ci & 1);
        const int yi = y0 + (ci >> 1);
        const float wx = (ci & 1) ? fx : (1.f - fx);
        const float wy = (ci >> 1) ? fy : (1.f - fy);
        const bool inb = (xi >= 0) && (xi < W) && (yi >= 0) && (yi < H);
        if (inb) {
          sv = fmaf(wx * wy, vbase[(size_t)(yi * W + xi) * DMODEL], sv);
        }
      }
      acc = fmaf(lv[l * 4 + p] * inv, sv, acc);
    }
  }
  outp[base * 256 + h * 32 + d] = acc;
}

// ---------------------------------------------------------------- LayerNorm
// One block (256 thr) per row; src already contains residual sum.
__global__ __launch_bounds__(256) void ln_k(const float* __restrict__ src,
                                            const float* __restrict__ w,
                                            const float* __restrict__ bias,
                                            float* __restrict__ dst) {
  const int row = blockIdx.x;
  const int tid = threadIdx.x;
  __shared__ float red[256];
  const float x = src[(size_t)row * DMODEL + tid];
  red[tid] = x;
  __syncthreads();
  for (int off = 128; off > 0; off >>= 1) {
    if (tid < off) red[tid] += red[tid + off];
    __syncthreads();
  }
  const float mu = red[0] * (1.f / DMODEL);
  __syncthreads();
  const float v = x - mu;
  red[tid] = v * v;
  __syncthreads();
  for (int off = 128; off > 0; off >>= 1) {
    if (tid < off) red[tid] += red[tid + off];
    __syncthreads();
  }
  const float var = red[0] * (1.f / DMODEL);
  dst[(size_t)row * DMODEL + tid] = v * rsqrtf(var + EPS_LN) * w[tid] + bias[tid];
}

// ---------------------------------------------------------------- launcher
extern "C" void kernel_launch(void* const* d_in, const int* in_sizes, int n_in,
                              void* d_out, int out_size, void* d_ws, size_t ws_size,
                              hipStream_t stream) {
  const float* tgt     = (const float*)d_in[0];
  const float* refp    = (const float*)d_in[1];
  const float* src     = (const float*)d_in[2];
  const float* vr      = (const float*)d_in[3];
  const float* qpos    = (const float*)d_in[4];
  const float* sa_in_w = (const float*)d_in[5];
  const float* sa_in_b = (const float*)d_in[6];
  const float* sa_out_w= (const float*)d_in[7];
  const float* sa_out_b= (const float*)d_in[8];
  const float* samp_w  = (const float*)d_in[9];
  const float* samp_b  = (const float*)d_in[10];
  const float* attn_w  = (const float*)d_in[11];
  const float* attn_b  = (const float*)d_in[12];
  const float* val_w   = (const float*)d_in[13];
  const float* val_b   = (const float*)d_in[14];
  const float* ca_out_w= (const float*)d_in[15];
  const float* ca_out_b= (const float*)d_in[16];
  const float* ffn1_w  = (const float*)d_in[17];
  const float* ffn1_b  = (const float*)d_in[18];
  const float* ffn2_w  = (const float*)d_in[19];
  const float* ffn2_b  = (const float*)d_in[20];
  const float* ln1_w   = (const float*)d_in[21];
  const float* ln1_b   = (const float*)d_in[22];
  const float* ln2_w   = (const float*)d_in[23];
  const float* ln2_b   = (const float*)d_in[24];
  const float* ln3_w   = (const float*)d_in[25];
  const float* ln3_b   = (const float*)d_in[26];

  const int M = BS * NQ;                 // 3600
  const size_t TOK = (size_t)M * DMODEL; // 921600

  float* ws = (float*)d_ws;
  size_t off = 0;
  auto alloc = [&](size_t n) { float* p = ws + off; off += n; return p; };
  float* cur   = alloc(TOK);
  float* qbuf  = alloc(TOK);
  float* qh    = alloc(TOK);
  float* kh    = alloc(TOK);
  float* vh    = alloc(TOK);
  float* sao   = alloc(TOK);
  float* tmp   = alloc(TOK);
  float* offb  = alloc(TOK);
  float* msda  = alloc(TOK);
  float* attl  = alloc((size_t)M * 128);
  float* value = alloc((size_t)BS * SLEN * DMODEL);
  float* ffnh  = alloc((size_t)M * DFF);

  const int n4 = (int)(TOK / 4);
  const dim3 blk(256);

  copy_k<<<dim3((n4 + 255) / 256), blk, 0, stream>>>(tgt, cur, n4);

  for (int l = 0; l < NLAYERS; ++l) {
    const float* wq = sa_in_w + (size_t)l * 768 * 256;
    const float* bq = sa_in_b + (size_t)l * 768;
    const float* wo = sa_out_w + (size_t)l * 256 * 256;
    const float* bo = sa_out_b + (size_t)l * 256;

    // q = cur + query_pos
    add_k<<<dim3((n4 + 255) / 256), blk, 0, stream>>>(cur, qpos, qbuf, n4);

    dim3 g1((M + 63) / 64, 256 / 64);
    gemm_k<<<g1, blk, 0, stream>>>(qbuf, wq,            bq,       nullptr, qh, M, 256, 256, 0);
    gemm_k<<<g1, blk, 0, stream>>>(qbuf, wq + 256*256,  bq + 256, nullptr, kh, M, 256, 256, 0);
    gemm_k<<<g1, blk, 0, stream>>>(cur,  wq + 512*256,  bq + 512, nullptr, vh, M, 256, 256, 0);

    attn_k<<<dim3(NQ, HEADS, BS), blk, 0, stream>>>(qh, kh, vh, sao);

    gemm_k<<<g1, blk, 0, stream>>>(sao, wo, bo, cur, tmp, M, 256, 256, 0);
    ln_k<<<dim3(M), blk, 0, stream>>>(tmp, ln1_w + l * 256, ln1_b + l * 256, cur);

    // cross-attn (MSDA)
    add_k<<<dim3((n4 + 255) / 256), blk, 0, stream>>>(cur, qpos, qbuf, n4);

    const int MV = BS * SLEN;  // 78240
    gemm_k<<<dim3((MV + 63) / 64, 256 / 64), blk, 0, stream>>>(
        src, val_w + (size_t)l * 256 * 256, val_b + l * 256, nullptr, value, MV, 256, 256, 0);
    gemm_k<<<g1, blk, 0, stream>>>(qbuf, samp_w + (size_t)l * 256 * 256, samp_b + l * 256,
                                   nullptr, offb, M, 256, 256, 0);
    gemm_k<<<dim3((M + 63) / 64, 128 / 64), blk, 0, stream>>>(
        qbuf, attn_w + (size_t)l * 128 * 256, attn_b + l * 128, nullptr, attl, M, 128, 256, 0);

    msda_k<<<dim3(NQ, BS), blk, 0, stream>>>(refp, vr, value, offb, attl, msda);

    gemm_k<<<g1, blk, 0, stream>>>(msda, ca_out_w + (size_t)l * 256 * 256,
                                   ca_out_b + l * 256, cur, tmp, M, 256, 256, 0);
    ln_k<<<dim3(M), blk, 0, stream>>>(tmp, ln2_w + l * 256, ln2_b + l * 256, cur);

    // FFN
    gemm_k<<<dim3((M + 63) / 64, DFF / 64), blk, 0, stream>>>(
        cur, ffn1_w + (size_t)l * DFF * 256, ffn1_b + l * DFF, nullptr, ffnh, M, DFF, 256, 1);
    gemm_k<<<g1, blk, 0, stream>>>(ffnh, ffn2_w + (size_t)l * 256 * DFF,
                                   ffn2_b + l * 256, cur, tmp, M, 256, DFF, 0);
    ln_k<<<dim3(M), blk, 0, stream>>>(tmp, ln3_w + l * 256, ln3_b + l * 256, cur);
  }

  copy_k<<<dim3((n4 + 255) / 256), blk, 0, stream>>>(cur, (float*)d_out, n4);
}

// Round 2
// 3184.972 us; speedup vs baseline: 2.2432x; 2.2432x over previous
//
#include <hip/hip_runtime.h>
#include <math.h>

#define DMODEL 256
#define HEADS 8
#define DHEAD 32
#define LEVELS 4
#define POINTS 4
#define NLAYERS 6
#define DFF 1024
#define BS 4
#define NQ 900
#define SLEN 19560
#define EPS_LN 1e-5f
#define ATT_SCALE 0.17677669529663689f

typedef __attribute__((ext_vector_type(8))) short bf16x8;
typedef __attribute__((ext_vector_type(4))) float f32x4;
typedef __attribute__((ext_vector_type(4))) unsigned short u16x4;
typedef __attribute__((ext_vector_type(8))) unsigned short u16x8;

__device__ __forceinline__ unsigned short f2b(float x) {
  unsigned u = __float_as_uint(x);
  u += 0x7FFF + ((u >> 16) & 1);
  return (unsigned short)(u >> 16);
}
__device__ __forceinline__ float b2f(unsigned short v) {
  return __uint_as_float(((unsigned)v) << 16);
}

// ---------------------------------------------------------------- elementwise
__global__ __launch_bounds__(256) void add_k(const float* __restrict__ a,
                                             const float* __restrict__ b,
                                             float* __restrict__ c, int n4) {
  int i = blockIdx.x * 256 + threadIdx.x;
  if (i < n4) {
    float4 av = reinterpret_cast<const float4*>(a)[i];
    float4 bv = reinterpret_cast<const float4*>(b)[i];
    float4 cv = {av.x + bv.x, av.y + bv.y, av.z + bv.z, av.w + bv.w};
    reinterpret_cast<float4*>(c)[i] = cv;
  }
}

__global__ __launch_bounds__(256) void copy_k(const float* __restrict__ a,
                                              float* __restrict__ c, int n4) {
  int i = blockIdx.x * 256 + threadIdx.x;
  if (i < n4) reinterpret_cast<float4*>(c)[i] = reinterpret_cast<const float4*>(a)[i];
}

__global__ __launch_bounds__(256) void f2b_k(const float* __restrict__ in,
                                             unsigned short* __restrict__ out, int n4) {
  for (int i = blockIdx.x * 256 + threadIdx.x; i < n4; i += gridDim.x * 256) {
    float4 v = reinterpret_cast<const float4*>(in)[i];
    u16x4 o4 = {f2b(v.x), f2b(v.y), f2b(v.z), f2b(v.w)};
    reinterpret_cast<u16x4*>(out)[i] = o4;
  }
}

// ---------------------------------------------------------------- fp32 GEMM
// C[M,N] = A[M,K] @ W[N,K]^T + bias[N] (+ res[M,N]) (+ relu)
__global__ __launch_bounds__(256) void gemm_k(const float* __restrict__ A,
                                              const float* __restrict__ W,
                                              const float* __restrict__ bias,
                                              const float* __restrict__ res,
                                              float* __restrict__ C,
                                              int M, int N, int K, int relu) {
  __shared__ float As[64][17];
  __shared__ float Bs[16][65];
  const int tid = threadIdx.x;
  const int tr = tid >> 4, tc = tid & 15;
  const int bm = blockIdx.x, bn = blockIdx.y;
  const int arow = tid >> 2;
  const int acol = (tid & 3) << 2;
  const int grow = bm * 64 + arow;
  const bool aval = grow < M;
  const int wrow = bn * 64 + arow;

  float acc[4][4] = {};
  for (int k0 = 0; k0 < K; k0 += 16) {
    float4 av = aval ? *reinterpret_cast<const float4*>(A + (size_t)grow * K + k0 + acol)
                     : float4{0.f, 0.f, 0.f, 0.f};
    float4 wv = *reinterpret_cast<const float4*>(W + (size_t)wrow * K + k0 + acol);
    As[arow][acol + 0] = av.x; As[arow][acol + 1] = av.y;
    As[arow][acol + 2] = av.z; As[arow][acol + 3] = av.w;
    Bs[acol + 0][arow] = wv.x; Bs[acol + 1][arow] = wv.y;
    Bs[acol + 2][arow] = wv.z; Bs[acol + 3][arow] = wv.w;
    __syncthreads();
#pragma unroll
    for (int kk = 0; kk < 16; ++kk) {
      float a[4], b[4];
#pragma unroll
      for (int i = 0; i < 4; ++i) a[i] = As[tr * 4 + i][kk];
#pragma unroll
      for (int j = 0; j < 4; ++j) b[j] = Bs[kk][tc * 4 + j];
#pragma unroll
      for (int i = 0; i < 4; ++i)
#pragma unroll
        for (int j = 0; j < 4; ++j) acc[i][j] = fmaf(a[i], b[j], acc[i][j]);
    }
    __syncthreads();
  }
#pragma unroll
  for (int i = 0; i < 4; ++i) {
    int m = bm * 64 + tr * 4 + i;
    if (m >= M) continue;
#pragma unroll
    for (int j = 0; j < 4; ++j) {
      int n = bn * 64 + tc * 4 + j;
      float v = acc[i][j] + bias[n];
      if (res) v += res[(size_t)m * N + n];
      if (relu) v = fmaxf(v, 0.f);
      C[(size_t)m * N + n] = v;
    }
  }
}

// ---------------------------------------------------------------- bf16 MFMA GEMM (value proj)
// C_bf16[M,256] = A_bf16[M,256] @ W_bf16[256,256]^T + bias_f32
__global__ __launch_bounds__(256) void gemm_vmfma_k(const unsigned short* __restrict__ A,
                                                    const unsigned short* __restrict__ W,
                                                    const float* __restrict__ bias,
                                                    unsigned short* __restrict__ C,
                                                    int M) {
  __shared__ unsigned short As[128][72];  // pad 72: frag reads ~2-way banks
  __shared__ unsigned short Ws[128][72];
  const int tid = threadIdx.x;
  const int lane = tid & 63, wv = tid >> 6;
  const int wm = wv >> 1, wn = wv & 1;  // 2x2 wave grid, each 64x64
  const int m0 = blockIdx.x * 128, n0 = blockIdx.y * 128;
  const int l15 = lane & 15, l4 = lane >> 4;

  f32x4 acc[4][4] = {};

  for (int k0 = 0; k0 < 256; k0 += 64) {
#pragma unroll
    for (int t = 0; t < 4; ++t) {
      int u = t * 256 + tid;       // 16B unit, 0..1023
      int r = u >> 3, c8 = u & 7;  // row, 8-elem col group
      int ra = m0 + r; if (ra >= M) ra = M - 1;
      *(u16x8*)&As[r][c8 * 8] =
          *(const u16x8*)(A + (size_t)ra * 256 + k0 + c8 * 8);
      *(u16x8*)&Ws[r][c8 * 8] =
          *(const u16x8*)(W + (size_t)(n0 + r) * 256 + k0 + c8 * 8);
    }
    __syncthreads();
#pragma unroll
    for (int ks = 0; ks < 64; ks += 32) {
      bf16x8 af[4], bf[4];
#pragma unroll
      for (int fr = 0; fr < 4; ++fr)
        af[fr] = *(const bf16x8*)&As[wm * 64 + fr * 16 + l15][ks + l4 * 8];
#pragma unroll
      for (int fn = 0; fn < 4; ++fn)
        bf[fn] = *(const bf16x8*)&Ws[wn * 64 + fn * 16 + l15][ks + l4 * 8];
#pragma unroll
      for (int fr = 0; fr < 4; ++fr)
#pragma unroll
        for (int fn = 0; fn < 4; ++fn)
          acc[fr][fn] = __builtin_amdgcn_mfma_f32_16x16x32_bf16(
              af[fr], bf[fn], acc[fr][fn], 0, 0, 0);
    }
    __syncthreads();
  }
#pragma unroll
  for (int fr = 0; fr < 4; ++fr)
#pragma unroll
    for (int fn = 0; fn < 4; ++fn) {
      int col = n0 + wn * 64 + fn * 16 + l15;
      float bs = bias[col];
#pragma unroll
      for (int j = 0; j < 4; ++j) {
        int row = m0 + wm * 64 + fr * 16 + l4 * 4 + j;
        if (row < M) C[(size_t)row * 256 + col] = f2b(acc[fr][fn][j] + bs);
      }
    }
}

// ---------------------------------------------------------------- flash self-attn
// grid (ceil(NQ/64), HEADS, BS); 256 thr = 16 row-groups x 16 col-groups.
#define QT 64
#define KTI 64
__global__ __launch_bounds__(256) void fattn_k(const float* __restrict__ qh,
                                               const float* __restrict__ kh,
                                               const float* __restrict__ vh,
                                               float* __restrict__ o) {
  __shared__ float Qs[QT][36];        // scaled Q, padded
  __shared__ float Kt[32][KTI + 4];   // K transposed [d][c]
  __shared__ float Vs[KTI][36];
  __shared__ float Ps[QT][68];
  const int tid = threadIdx.x;
  const int tr = tid >> 4, tc = tid & 15;
  const int q0 = blockIdx.x * QT;
  const int h = blockIdx.y, b = blockIdx.z;
  const size_t hoff = (size_t)h * DHEAD;

#pragma unroll
  for (int t = 0; t < 2; ++t) {
    int u = t * 256 + tid;
    int r = u >> 3, c4 = u & 7;
    int q = q0 + r;
    float4 v = {0.f, 0.f, 0.f, 0.f};
    if (q < NQ) v = *(const float4*)(qh + (size_t)(b * NQ + q) * DMODEL + hoff + c4 * 4);
    v.x *= ATT_SCALE; v.y *= ATT_SCALE; v.z *= ATT_SCALE; v.w *= ATT_SCALE;
    *(float4*)&Qs[r][c4 * 4] = v;
  }
  float m_r[4], l_r[4], acc0[4], acc1[4];
#pragma unroll
  for (int i = 0; i < 4; ++i) { m_r[i] = -1e30f; l_r[i] = 0.f; acc0[i] = 0.f; acc1[i] = 0.f; }
  __syncthreads();

  for (int k0 = 0; k0 < NQ; k0 += KTI) {
#pragma unroll
    for (int t = 0; t < 2; ++t) {
      int u = t * 256 + tid;
      int r = u >> 3, c4 = u & 7;
      int kk = k0 + r;
      int kc = kk < NQ ? kk : NQ - 1;
      const size_t gof = (size_t)(b * NQ + kc) * DMODEL + hoff + c4 * 4;
      float4 kv = *(const float4*)(kh + gof);
      float4 vv = *(const float4*)(vh + gof);
      if (kk >= NQ) { kv = {0.f, 0.f, 0.f, 0.f}; vv = {0.f, 0.f, 0.f, 0.f}; }
      Kt[c4 * 4 + 0][r] = kv.x; Kt[c4 * 4 + 1][r] = kv.y;
      Kt[c4 * 4 + 2][r] = kv.z; Kt[c4 * 4 + 3][r] = kv.w;
      *(float4*)&Vs[r][c4 * 4] = vv;
    }
    __syncthreads();

    // S micro-tile: rows tr*4+i, cols tc*4+j
    float s_[4][4] = {};
#pragma unroll
    for (int d4 = 0; d4 < 8; ++d4) {
      float4 q4[4];
#pragma unroll
      for (int i = 0; i < 4; ++i) q4[i] = *(float4*)&Qs[tr * 4 + i][d4 * 4];
      float4 k0v = *(float4*)&Kt[d4 * 4 + 0][tc * 4];
      float4 k1v = *(float4*)&Kt[d4 * 4 + 1][tc * 4];
      float4 k2v = *(float4*)&Kt[d4 * 4 + 2][tc * 4];
      float4 k3v = *(float4*)&Kt[d4 * 4 + 3][tc * 4];
#pragma unroll
      for (int i = 0; i < 4; ++i) {
        s_[i][0] = fmaf(q4[i].x, k0v.x, fmaf(q4[i].y, k1v.x, fmaf(q4[i].z, k2v.x, fmaf(q4[i].w, k3v.x, s_[i][0]))));
        s_[i][1] = fmaf(q4[i].x, k0v.y, fmaf(q4[i].y, k1v.y, fmaf(q4[i].z, k2v.y, fmaf(q4[i].w, k3v.y, s_[i][1]))));
        s_[i][2] = fmaf(q4[i].x, k0v.z, fmaf(q4[i].y, k1v.z, fmaf(q4[i].z, k2v.z, fmaf(q4[i].w, k3v.z, s_[i][2]))));
        s_[i][3] = fmaf(q4[i].x, k0v.w, fmaf(q4[i].y, k1v.w, fmaf(q4[i].z, k2v.w, fmaf(q4[i].w, k3v.w, s_[i][3]))));
      }
    }
    const int cb = k0 + tc * 4;
#pragma unroll
    for (int j = 0; j < 4; ++j)
      if (cb + j >= NQ) {
#pragma unroll
        for (int i = 0; i < 4; ++i) s_[i][j] = -1e30f;
      }

#pragma unroll
    for (int i = 0; i < 4; ++i) {
      float tm = fmaxf(fmaxf(s_[i][0], s_[i][1]), fmaxf(s_[i][2], s_[i][3]));
      tm = fmaxf(tm, __shfl_xor(tm, 1, 16));
      tm = fmaxf(tm, __shfl_xor(tm, 2, 16));
      tm = fmaxf(tm, __shfl_xor(tm, 4, 16));
      tm = fmaxf(tm, __shfl_xor(tm, 8, 16));
      float mn = fmaxf(m_r[i], tm);
      float sf = __expf(m_r[i] - mn);
      m_r[i] = mn;
      acc0[i] *= sf; acc1[i] *= sf;
      float p0 = __expf(s_[i][0] - mn);
      float p1 = __expf(s_[i][1] - mn);
      float p2 = __expf(s_[i][2] - mn);
      float p3 = __expf(s_[i][3] - mn);
      *(float4*)&Ps[tr * 4 + i][tc * 4] = float4{p0, p1, p2, p3};
      float rs = p0 + p1 + p2 + p3;
      rs += __shfl_xor(rs, 1, 16);
      rs += __shfl_xor(rs, 2, 16);
      rs += __shfl_xor(rs, 4, 16);
      rs += __shfl_xor(rs, 8, 16);
      l_r[i] = l_r[i] * sf + rs;
    }

    // PV: P rows for this tr live in this wave — no barrier needed before reads
#pragma unroll
    for (int c0 = 0; c0 < KTI; c0 += 4) {
      float4 p4[4];
#pragma unroll
      for (int i = 0; i < 4; ++i) p4[i] = *(float4*)&Ps[tr * 4 + i][c0];
      float2 v0 = *(float2*)&Vs[c0 + 0][tc * 2];
      float2 v1 = *(float2*)&Vs[c0 + 1][tc * 2];
      float2 v2 = *(float2*)&Vs[c0 + 2][tc * 2];
      float2 v3 = *(float2*)&Vs[c0 + 3][tc * 2];
#pragma unroll
      for (int i = 0; i < 4; ++i) {
        acc0[i] = fmaf(p4[i].x, v0.x, fmaf(p4[i].y, v1.x, fmaf(p4[i].z, v2.x, fmaf(p4[i].w, v3.x, acc0[i]))));
        acc1[i] = fmaf(p4[i].x, v0.y, fmaf(p4[i].y, v1.y, fmaf(p4[i].z, v2.y, fmaf(p4[i].w, v3.y, acc1[i]))));
      }
    }
    __syncthreads();
  }

#pragma unroll
  for (int i = 0; i < 4; ++i) {
    int q = q0 + tr * 4 + i;
    if (q < NQ) {
      float inv = 1.f / l_r[i];
      *(float2*)(o + (size_t)(b * NQ + q) * DMODEL + hoff + tc * 2) =
          float2{acc0[i] * inv, acc1[i] * inv};
    }
  }
}

// ---------------------------------------------------------------- MSDA sample (bf16 value)
__global__ __launch_bounds__(256) void msda_k(const float* __restrict__ refp,
                                              const float* __restrict__ vr,
                                              const unsigned short* __restrict__ value,
                                              const float* __restrict__ offb,
                                              const float* __restrict__ attl,
                                              float* __restrict__ outp) {
  const int HW[4][2] = {{92, 160}, {46, 80}, {23, 40}, {12, 20}};
  const int START[4] = {0, 14720, 18400, 19320};
  const int qi = blockIdx.x, b = blockIdx.y;
  const int tid = threadIdx.x;
  const int h = tid >> 5, d = tid & 31;
  const size_t base = (size_t)(b * NQ + qi);
  const float rx = refp[base * 3 + 0];
  const float rz = refp[base * 3 + 2];

  const float* lg = attl + base * 128 + h * 16;
  float lv[16];
  float mx = -1e30f;
#pragma unroll
  for (int j = 0; j < 16; ++j) { lv[j] = lg[j]; mx = fmaxf(mx, lv[j]); }
  float sum = 0.f;
#pragma unroll
  for (int j = 0; j < 16; ++j) { lv[j] = __expf(lv[j] - mx); sum += lv[j]; }
  const float inv = 1.f / sum;

  const float* ob = offb + base * 256 + h * 32;
  float acc = 0.f;
#pragma unroll
  for (int l = 0; l < 4; ++l) {
    const int H = HW[l][0], W = HW[l][1];
    const float refx = rx * vr[(b * LEVELS + l) * 2 + 0];
    const float refy = rz * vr[(b * LEVELS + l) * 2 + 1];
    const unsigned short* vbase = value + ((size_t)b * SLEN + START[l]) * DMODEL + h * DHEAD + d;
#pragma unroll
    for (int p = 0; p < 4; ++p) {
      const float offx = ob[l * 8 + p * 2 + 0];
      const float offy = ob[l * 8 + p * 2 + 1];
      const float x = (refx + offx / (float)W) * (float)W - 0.5f;
      const float y = (refy + offy / (float)H) * (float)H - 0.5f;
      const float x0f = floorf(x), y0f = floorf(y);
      const float fx = x - x0f, fy = y - y0f;
      const int x0 = (int)x0f, y0 = (int)y0f;
      float sv = 0.f;
#pragma unroll
      for (int ci = 0; ci < 4; ++ci) {
        const int xi = x0 + (ci & 1);
        const int yi = y0 + (ci >> 1);
        const float wx = (ci & 1) ? fx : (1.f - fx);
        const float wy = (ci >> 1) ? fy : (1.f - fy);
        if ((xi >= 0) && (xi < W) && (yi >= 0) && (yi < H))
          sv = fmaf(wx * wy, b2f(vbase[(size_t)(yi * W + xi) * DMODEL]), sv);
      }
      acc = fmaf(lv[l * 4 + p] * inv, sv, acc);
    }
  }
  outp[base * 256 + h * 32 + d] = acc;
}

// ---------------------------------------------------------------- LayerNorm
__global__ __launch_bounds__(256) void ln_k(const float* __restrict__ src,
                                            const float* __restrict__ w,
                                            const float* __restrict__ bias,
                                            float* __restrict__ dst) {
  const int row = blockIdx.x;
  const int tid = threadIdx.x;
  __shared__ float red[256];
  const float x = src[(size_t)row * DMODEL + tid];
  red[tid] = x;
  __syncthreads();
  for (int off = 128; off > 0; off >>= 1) {
    if (tid < off) red[tid] += red[tid + off];
    __syncthreads();
  }
  const float mu = red[0] * (1.f / DMODEL);
  __syncthreads();
  const float v = x - mu;
  red[tid] = v * v;
  __syncthreads();
  for (int off = 128; off > 0; off >>= 1) {
    if (tid < off) red[tid] += red[tid + off];
    __syncthreads();
  }
  const float var = red[0] * (1.f / DMODEL);
  dst[(size_t)row * DMODEL + tid] = v * rsqrtf(var + EPS_LN) * w[tid] + bias[tid];
}

// ---------------------------------------------------------------- launcher
extern "C" void kernel_launch(void* const* d_in, const int* in_sizes, int n_in,
                              void* d_out, int out_size, void* d_ws, size_t ws_size,
                              hipStream_t stream) {
  const float* tgt     = (const float*)d_in[0];
  const float* refp    = (const float*)d_in[1];
  const float* src     = (const float*)d_in[2];
  const float* vr      = (const float*)d_in[3];
  const float* qpos    = (const float*)d_in[4];
  const float* sa_in_w = (const float*)d_in[5];
  const float* sa_in_b = (const float*)d_in[6];
  const float* sa_out_w= (const float*)d_in[7];
  const float* sa_out_b= (const float*)d_in[8];
  const float* samp_w  = (const float*)d_in[9];
  const float* samp_b  = (const float*)d_in[10];
  const float* attn_w  = (const float*)d_in[11];
  const float* attn_b  = (const float*)d_in[12];
  const float* val_w   = (const float*)d_in[13];
  const float* val_b   = (const float*)d_in[14];
  const float* ca_out_w= (const float*)d_in[15];
  const float* ca_out_b= (const float*)d_in[16];
  const float* ffn1_w  = (const float*)d_in[17];
  const float* ffn1_b  = (const float*)d_in[18];
  const float* ffn2_w  = (const float*)d_in[19];
  const float* ffn2_b  = (const float*)d_in[20];
  const float* ln1_w   = (const float*)d_in[21];
  const float* ln1_b   = (const float*)d_in[22];
  const float* ln2_w   = (const float*)d_in[23];
  const float* ln2_b   = (const float*)d_in[24];
  const float* ln3_w   = (const float*)d_in[25];
  const float* ln3_b   = (const float*)d_in[26];

  const int M = BS * NQ;                 // 3600
  const int MV = BS * SLEN;              // 78240
  const size_t TOK = (size_t)M * DMODEL; // 921600

  float* ws = (float*)d_ws;
  size_t off = 0;
  auto alloc = [&](size_t n) { float* p = ws + off; off += n; return p; };
  float* cur   = alloc(TOK);
  float* qbuf  = alloc(TOK);
  float* qh    = alloc(TOK);
  float* kh    = alloc(TOK);
  float* vh    = alloc(TOK);
  float* sao   = alloc(TOK);
  float* tmp   = alloc(TOK);
  float* offb  = alloc(TOK);
  float* msda  = alloc(TOK);
  float* attl  = alloc((size_t)M * 128);
  float* ffnh  = alloc((size_t)M * DFF);
  unsigned short* src_bf  = (unsigned short*)alloc((size_t)MV * DMODEL / 2);
  unsigned short* valw_bf = (unsigned short*)alloc((size_t)NLAYERS * DMODEL * DMODEL / 2);
  unsigned short* value_bf= (unsigned short*)alloc((size_t)MV * DMODEL / 2);

  const int n4 = (int)(TOK / 4);
  const dim3 blk(256);

  copy_k<<<dim3((n4 + 255) / 256), blk, 0, stream>>>(tgt, cur, n4);
  // one-time bf16 conversions
  f2b_k<<<dim3(2048), blk, 0, stream>>>(src, src_bf, MV * DMODEL / 4);
  f2b_k<<<dim3(384), blk, 0, stream>>>(val_w, valw_bf, NLAYERS * DMODEL * DMODEL / 4);

  for (int l = 0; l < NLAYERS; ++l) {
    const float* wq = sa_in_w + (size_t)l * 768 * 256;
    const float* bq = sa_in_b + (size_t)l * 768;
    const float* wo = sa_out_w + (size_t)l * 256 * 256;
    const float* bo = sa_out_b + (size_t)l * 256;

    add_k<<<dim3((n4 + 255) / 256), blk, 0, stream>>>(cur, qpos, qbuf, n4);

    dim3 g1((M + 63) / 64, 256 / 64);
    gemm_k<<<g1, blk, 0, stream>>>(qbuf, wq,           bq,       nullptr, qh, M, 256, 256, 0);
    gemm_k<<<g1, blk, 0, stream>>>(qbuf, wq + 256*256, bq + 256, nullptr, kh, M, 256, 256, 0);
    gemm_k<<<g1, blk, 0, stream>>>(cur,  wq + 512*256, bq + 512, nullptr, vh, M, 256, 256, 0);

    fattn_k<<<dim3((NQ + QT - 1) / QT, HEADS, BS), blk, 0, stream>>>(qh, kh, vh, sao);

    gemm_k<<<g1, blk, 0, stream>>>(sao, wo, bo, cur, tmp, M, 256, 256, 0);
    ln_k<<<dim3(M), blk, 0, stream>>>(tmp, ln1_w + l * 256, ln1_b + l * 256, cur);

    // cross-attn (MSDA)
    add_k<<<dim3((n4 + 255) / 256), blk, 0, stream>>>(cur, qpos, qbuf, n4);

    gemm_vmfma_k<<<dim3((MV + 127) / 128, 2), blk, 0, stream>>>(
        src_bf, valw_bf + (size_t)l * 256 * 256, val_b + l * 256, value_bf, MV);
    gemm_k<<<g1, blk, 0, stream>>>(qbuf, samp_w + (size_t)l * 256 * 256, samp_b + l * 256,
                                   nullptr, offb, M, 256, 256, 0);
    gemm_k<<<dim3((M + 63) / 64, 128 / 64), blk, 0, stream>>>(
        qbuf, attn_w + (size_t)l * 128 * 256, attn_b + l * 128, nullptr, attl, M, 128, 256, 0);

    msda_k<<<dim3(NQ, BS), blk, 0, stream>>>(refp, vr, value_bf, offb, attl, msda);

    gemm_k<<<g1, blk, 0, stream>>>(msda, ca_out_w + (size_t)l * 256 * 256,
                                   ca_out_b + l * 256, cur, tmp, M, 256, 256, 0);
    ln_k<<<dim3(M), blk, 0, stream>>>(tmp, ln2_w + l * 256, ln2_b + l * 256, cur);

    // FFN
    gemm_k<<<dim3((M + 63) / 64, DFF / 64), blk, 0, stream>>>(
        cur, ffn1_w + (size_t)l * DFF * 256, ffn1_b + l * DFF, nullptr, ffnh, M, DFF, 256, 1);
    gemm_k<<<g1, blk, 0, stream>>>(ffnh, ffn2_w + (size_t)l * 256 * DFF,
                                   ffn2_b + l * 256, cur, tmp, M, 256, DFF, 0);
    ln_k<<<dim3(M), blk, 0, stream>>>(tmp, ln3_w + l * 256, ln3_b + l * 256, cur);
  }

  copy_k<<<dim3((n4 + 255) / 256), blk, 0, stream>>>(cur, (float*)d_out, n4);
}

// Round 3
// 2149.408 us; speedup vs baseline: 3.3240x; 1.4818x over previous
//
#include <hip/hip_runtime.h>
#include <math.h>

#define DMODEL 256
#define HEADS 8
#define DHEAD 32
#define LEVELS 4
#define POINTS 4
#define NLAYERS 6
#define DFF 1024
#define BS 4
#define NQ 900
#define SLEN 19560
#define EPS_LN 1e-5f
#define ATT_SCALE 0.17677669529663689f

typedef __attribute__((ext_vector_type(8))) short bf16x8;
typedef __attribute__((ext_vector_type(4))) float f32x4;
typedef __attribute__((ext_vector_type(4))) unsigned short u16x4;
typedef __attribute__((ext_vector_type(8))) unsigned short u16x8;

__device__ __forceinline__ unsigned short f2b(float x) {
  unsigned u = __float_as_uint(x);
  u += 0x7FFF + ((u >> 16) & 1);
  return (unsigned short)(u >> 16);
}
__device__ __forceinline__ float b2f(unsigned short v) {
  return __uint_as_float(((unsigned)v) << 16);
}

// ---------------------------------------------------------------- elementwise
__global__ __launch_bounds__(256) void copycvt_k(const float* __restrict__ a,
                                                 float* __restrict__ cf,
                                                 unsigned short* __restrict__ cb, int n4) {
  int i = blockIdx.x * 256 + threadIdx.x;
  if (i < n4) {
    float4 v = reinterpret_cast<const float4*>(a)[i];
    reinterpret_cast<float4*>(cf)[i] = v;
    u16x4 o4 = {f2b(v.x), f2b(v.y), f2b(v.z), f2b(v.w)};
    reinterpret_cast<u16x4*>(cb)[i] = o4;
  }
}

__global__ __launch_bounds__(256) void addcvt_k(const float* __restrict__ a,
                                                const float* __restrict__ b,
                                                unsigned short* __restrict__ cb, int n4) {
  int i = blockIdx.x * 256 + threadIdx.x;
  if (i < n4) {
    float4 av = reinterpret_cast<const float4*>(a)[i];
    float4 bv = reinterpret_cast<const float4*>(b)[i];
    u16x4 o4 = {f2b(av.x + bv.x), f2b(av.y + bv.y), f2b(av.z + bv.z), f2b(av.w + bv.w)};
    reinterpret_cast<u16x4*>(cb)[i] = o4;
  }
}

__global__ __launch_bounds__(256) void copy_k(const float* __restrict__ a,
                                              float* __restrict__ c, int n4) {
  int i = blockIdx.x * 256 + threadIdx.x;
  if (i < n4) reinterpret_cast<float4*>(c)[i] = reinterpret_cast<const float4*>(a)[i];
}

__global__ __launch_bounds__(256) void f2b_k(const float* __restrict__ in,
                                             unsigned short* __restrict__ out, int n4) {
  for (int i = blockIdx.x * 256 + threadIdx.x; i < n4; i += gridDim.x * 256) {
    float4 v = reinterpret_cast<const float4*>(in)[i];
    u16x4 o4 = {f2b(v.x), f2b(v.y), f2b(v.z), f2b(v.w)};
    reinterpret_cast<u16x4*>(out)[i] = o4;
  }
}

// ---------------------------------------------------------------- bf16 MFMA GEMM, 64x64 tile
// C[M,N] = A_bf[M,K] @ W_bf[N,K]^T + bias; optional f32 res; optional relu;
// writes outf (f32) and/or outb (bf16). N multiple of 64, K multiple of 64.
__global__ __launch_bounds__(256) void gemm_bf_k(const unsigned short* __restrict__ A,
                                                 const unsigned short* __restrict__ W,
                                                 const float* __restrict__ bias,
                                                 const float* __restrict__ res,
                                                 float* __restrict__ outf,
                                                 unsigned short* __restrict__ outb,
                                                 int M, int N, int K, int relu) {
  __shared__ unsigned short As[64][72];
  __shared__ unsigned short Ws[64][72];
  const int tid = threadIdx.x;
  const int lane = tid & 63, wv = tid >> 6;
  const int wm = wv >> 1, wn = wv & 1;  // 2x2 waves, each 32x32 out
  const int m0 = blockIdx.x * 64, n0 = blockIdx.y * 64;
  const int l15 = lane & 15, l4 = lane >> 4;

  f32x4 acc[2][2] = {};
  for (int k0 = 0; k0 < K; k0 += 64) {
#pragma unroll
    for (int t = 0; t < 2; ++t) {
      int u = t * 256 + tid;
      int r = u >> 3, c8 = u & 7;
      int ra = m0 + r; if (ra >= M) ra = M - 1;
      *(u16x8*)&As[r][c8 * 8] = *(const u16x8*)(A + (size_t)ra * K + k0 + c8 * 8);
      *(u16x8*)&Ws[r][c8 * 8] = *(const u16x8*)(W + (size_t)(n0 + r) * K + k0 + c8 * 8);
    }
    __syncthreads();
#pragma unroll
    for (int ks = 0; ks < 64; ks += 32) {
      bf16x8 af[2], wf[2];
#pragma unroll
      for (int fr = 0; fr < 2; ++fr)
        af[fr] = *(const bf16x8*)&As[wm * 32 + fr * 16 + l15][ks + l4 * 8];
#pragma unroll
      for (int fn = 0; fn < 2; ++fn)
        wf[fn] = *(const bf16x8*)&Ws[wn * 32 + fn * 16 + l15][ks + l4 * 8];
#pragma unroll
      for (int fr = 0; fr < 2; ++fr)
#pragma unroll
        for (int fn = 0; fn < 2; ++fn)
          acc[fr][fn] = __builtin_amdgcn_mfma_f32_16x16x32_bf16(
              af[fr], wf[fn], acc[fr][fn], 0, 0, 0);
    }
    __syncthreads();
  }
#pragma unroll
  for (int fr = 0; fr < 2; ++fr)
#pragma unroll
    for (int fn = 0; fn < 2; ++fn) {
      int col = n0 + wn * 32 + fn * 16 + l15;
      float bs = bias[col];
#pragma unroll
      for (int j = 0; j < 4; ++j) {
        int row = m0 + wm * 32 + fr * 16 + l4 * 4 + j;
        if (row >= M) continue;
        float v = acc[fr][fn][j] + bs;
        if (res) v += res[(size_t)row * N + col];
        if (relu) v = fmaxf(v, 0.f);
        if (outf) outf[(size_t)row * N + col] = v;
        if (outb) outb[(size_t)row * N + col] = f2b(v);
      }
    }
}

// ---------------------------------------------------------------- bf16 MFMA GEMM (value proj, 128x128)
__global__ __launch_bounds__(256) void gemm_vmfma_k(const unsigned short* __restrict__ A,
                                                    const unsigned short* __restrict__ W,
                                                    const float* __restrict__ bias,
                                                    unsigned short* __restrict__ C,
                                                    int M) {
  __shared__ unsigned short As[128][72];
  __shared__ unsigned short Ws[128][72];
  const int tid = threadIdx.x;
  const int lane = tid & 63, wv = tid >> 6;
  const int wm = wv >> 1, wn = wv & 1;
  const int m0 = blockIdx.x * 128, n0 = blockIdx.y * 128;
  const int l15 = lane & 15, l4 = lane >> 4;

  f32x4 acc[4][4] = {};

  for (int k0 = 0; k0 < 256; k0 += 64) {
#pragma unroll
    for (int t = 0; t < 4; ++t) {
      int u = t * 256 + tid;
      int r = u >> 3, c8 = u & 7;
      int ra = m0 + r; if (ra >= M) ra = M - 1;
      *(u16x8*)&As[r][c8 * 8] = *(const u16x8*)(A + (size_t)ra * 256 + k0 + c8 * 8);
      *(u16x8*)&Ws[r][c8 * 8] = *(const u16x8*)(W + (size_t)(n0 + r) * 256 + k0 + c8 * 8);
    }
    __syncthreads();
#pragma unroll
    for (int ks = 0; ks < 64; ks += 32) {
      bf16x8 af[4], bf[4];
#pragma unroll
      for (int fr = 0; fr < 4; ++fr)
        af[fr] = *(const bf16x8*)&As[wm * 64 + fr * 16 + l15][ks + l4 * 8];
#pragma unroll
      for (int fn = 0; fn < 4; ++fn)
        bf[fn] = *(const bf16x8*)&Ws[wn * 64 + fn * 16 + l15][ks + l4 * 8];
#pragma unroll
      for (int fr = 0; fr < 4; ++fr)
#pragma unroll
        for (int fn = 0; fn < 4; ++fn)
          acc[fr][fn] = __builtin_amdgcn_mfma_f32_16x16x32_bf16(
              af[fr], bf[fn], acc[fr][fn], 0, 0, 0);
    }
    __syncthreads();
  }
#pragma unroll
  for (int fr = 0; fr < 4; ++fr)
#pragma unroll
    for (int fn = 0; fn < 4; ++fn) {
      int col = n0 + wn * 64 + fn * 16 + l15;
      float bs = bias[col];
#pragma unroll
      for (int j = 0; j < 4; ++j) {
        int row = m0 + wm * 64 + fr * 16 + l4 * 4 + j;
        if (row < M) C[(size_t)row * 256 + col] = f2b(acc[fr][fn][j] + bs);
      }
    }
}

// ---------------------------------------------------------------- flash self-attn (fp32, bf16 out)
#define QT 64
#define KTI 64
__global__ __launch_bounds__(256) void fattn_k(const float* __restrict__ qh,
                                               const float* __restrict__ kh,
                                               const float* __restrict__ vh,
                                               unsigned short* __restrict__ o) {
  __shared__ float Qs[QT][36];
  __shared__ float Kt[32][KTI + 4];
  __shared__ float Vs[KTI][36];
  __shared__ float Ps[QT][68];
  const int tid = threadIdx.x;
  const int tr = tid >> 4, tc = tid & 15;
  const int q0 = blockIdx.x * QT;
  const int h = blockIdx.y, b = blockIdx.z;
  const size_t hoff = (size_t)h * DHEAD;

#pragma unroll
  for (int t = 0; t < 2; ++t) {
    int u = t * 256 + tid;
    int r = u >> 3, c4 = u & 7;
    int q = q0 + r;
    float4 v = {0.f, 0.f, 0.f, 0.f};
    if (q < NQ) v = *(const float4*)(qh + (size_t)(b * NQ + q) * DMODEL + hoff + c4 * 4);
    v.x *= ATT_SCALE; v.y *= ATT_SCALE; v.z *= ATT_SCALE; v.w *= ATT_SCALE;
    *(float4*)&Qs[r][c4 * 4] = v;
  }
  float m_r[4], l_r[4], acc0[4], acc1[4];
#pragma unroll
  for (int i = 0; i < 4; ++i) { m_r[i] = -1e30f; l_r[i] = 0.f; acc0[i] = 0.f; acc1[i] = 0.f; }
  __syncthreads();

  for (int k0 = 0; k0 < NQ; k0 += KTI) {
#pragma unroll
    for (int t = 0; t < 2; ++t) {
      int u = t * 256 + tid;
      int r = u >> 3, c4 = u & 7;
      int kk = k0 + r;
      int kc = kk < NQ ? kk : NQ - 1;
      const size_t gof = (size_t)(b * NQ + kc) * DMODEL + hoff + c4 * 4;
      float4 kv = *(const float4*)(kh + gof);
      float4 vv = *(const float4*)(vh + gof);
      if (kk >= NQ) { kv = {0.f, 0.f, 0.f, 0.f}; vv = {0.f, 0.f, 0.f, 0.f}; }
      Kt[c4 * 4 + 0][r] = kv.x; Kt[c4 * 4 + 1][r] = kv.y;
      Kt[c4 * 4 + 2][r] = kv.z; Kt[c4 * 4 + 3][r] = kv.w;
      *(float4*)&Vs[r][c4 * 4] = vv;
    }
    __syncthreads();

    float s_[4][4] = {};
#pragma unroll
    for (int d4 = 0; d4 < 8; ++d4) {
      float4 q4[4];
#pragma unroll
      for (int i = 0; i < 4; ++i) q4[i] = *(float4*)&Qs[tr * 4 + i][d4 * 4];
      float4 k0v = *(float4*)&Kt[d4 * 4 + 0][tc * 4];
      float4 k1v = *(float4*)&Kt[d4 * 4 + 1][tc * 4];
      float4 k2v = *(float4*)&Kt[d4 * 4 + 2][tc * 4];
      float4 k3v = *(float4*)&Kt[d4 * 4 + 3][tc * 4];
#pragma unroll
      for (int i = 0; i < 4; ++i) {
        s_[i][0] = fmaf(q4[i].x, k0v.x, fmaf(q4[i].y, k1v.x, fmaf(q4[i].z, k2v.x, fmaf(q4[i].w, k3v.x, s_[i][0]))));
        s_[i][1] = fmaf(q4[i].x, k0v.y, fmaf(q4[i].y, k1v.y, fmaf(q4[i].z, k2v.y, fmaf(q4[i].w, k3v.y, s_[i][1]))));
        s_[i][2] = fmaf(q4[i].x, k0v.z, fmaf(q4[i].y, k1v.z, fmaf(q4[i].z, k2v.z, fmaf(q4[i].w, k3v.z, s_[i][2]))));
        s_[i][3] = fmaf(q4[i].x, k0v.w, fmaf(q4[i].y, k1v.w, fmaf(q4[i].z, k2v.w, fmaf(q4[i].w, k3v.w, s_[i][3]))));
      }
    }
    const int cb = k0 + tc * 4;
#pragma unroll
    for (int j = 0; j < 4; ++j)
      if (cb + j >= NQ) {
#pragma unroll
        for (int i = 0; i < 4; ++i) s_[i][j] = -1e30f;
      }

#pragma unroll
    for (int i = 0; i < 4; ++i) {
      float tm = fmaxf(fmaxf(s_[i][0], s_[i][1]), fmaxf(s_[i][2], s_[i][3]));
      tm = fmaxf(tm, __shfl_xor(tm, 1, 16));
      tm = fmaxf(tm, __shfl_xor(tm, 2, 16));
      tm = fmaxf(tm, __shfl_xor(tm, 4, 16));
      tm = fmaxf(tm, __shfl_xor(tm, 8, 16));
      float mn = fmaxf(m_r[i], tm);
      float sf = __expf(m_r[i] - mn);
      m_r[i] = mn;
      acc0[i] *= sf; acc1[i] *= sf;
      float p0 = __expf(s_[i][0] - mn);
      float p1 = __expf(s_[i][1] - mn);
      float p2 = __expf(s_[i][2] - mn);
      float p3 = __expf(s_[i][3] - mn);
      *(float4*)&Ps[tr * 4 + i][tc * 4] = float4{p0, p1, p2, p3};
      float rs = p0 + p1 + p2 + p3;
      rs += __shfl_xor(rs, 1, 16);
      rs += __shfl_xor(rs, 2, 16);
      rs += __shfl_xor(rs, 4, 16);
      rs += __shfl_xor(rs, 8, 16);
      l_r[i] = l_r[i] * sf + rs;
    }

#pragma unroll
    for (int c0 = 0; c0 < KTI; c0 += 4) {
      float4 p4[4];
#pragma unroll
      for (int i = 0; i < 4; ++i) p4[i] = *(float4*)&Ps[tr * 4 + i][c0];
      float2 v0 = *(float2*)&Vs[c0 + 0][tc * 2];
      float2 v1 = *(float2*)&Vs[c0 + 1][tc * 2];
      float2 v2 = *(float2*)&Vs[c0 + 2][tc * 2];
      float2 v3 = *(float2*)&Vs[c0 + 3][tc * 2];
#pragma unroll
      for (int i = 0; i < 4; ++i) {
        acc0[i] = fmaf(p4[i].x, v0.x, fmaf(p4[i].y, v1.x, fmaf(p4[i].z, v2.x, fmaf(p4[i].w, v3.x, acc0[i]))));
        acc1[i] = fmaf(p4[i].x, v0.y, fmaf(p4[i].y, v1.y, fmaf(p4[i].z, v2.y, fmaf(p4[i].w, v3.y, acc1[i]))));
      }
    }
    __syncthreads();
  }

#pragma unroll
  for (int i = 0; i < 4; ++i) {
    int q = q0 + tr * 4 + i;
    if (q < NQ) {
      float inv = 1.f / l_r[i];
      ushort2 ov;
      ov.x = f2b(acc0[i] * inv);
      ov.y = f2b(acc1[i] * inv);
      *(ushort2*)(o + (size_t)(b * NQ + q) * DMODEL + hoff + tc * 2) = ov;
    }
  }
}

// ---------------------------------------------------------------- MSDA sample (bf16 value, bf16 out)
__global__ __launch_bounds__(256) void msda_k(const float* __restrict__ refp,
                                              const float* __restrict__ vr,
                                              const unsigned short* __restrict__ value,
                                              const float* __restrict__ offb,
                                              const float* __restrict__ attl,
                                              unsigned short* __restrict__ outp) {
  const int HW[4][2] = {{92, 160}, {46, 80}, {23, 40}, {12, 20}};
  const int START[4] = {0, 14720, 18400, 19320};
  const int qi = blockIdx.x, b = blockIdx.y;
  const int tid = threadIdx.x;
  const int h = tid >> 5, d = tid & 31;
  const size_t base = (size_t)(b * NQ + qi);
  const float rx = refp[base * 3 + 0];
  const float rz = refp[base * 3 + 2];

  const float* lg = attl + base * 128 + h * 16;
  float lv[16];
  float mx = -1e30f;
#pragma unroll
  for (int j = 0; j < 16; ++j) { lv[j] = lg[j]; mx = fmaxf(mx, lv[j]); }
  float sum = 0.f;
#pragma unroll
  for (int j = 0; j < 16; ++j) { lv[j] = __expf(lv[j] - mx); sum += lv[j]; }
  const float inv = 1.f / sum;

  const float* ob = offb + base * 256 + h * 32;
  float acc = 0.f;
#pragma unroll
  for (int l = 0; l < 4; ++l) {
    const int H = HW[l][0], W = HW[l][1];
    const float refx = rx * vr[(b * LEVELS + l) * 2 + 0];
    const float refy = rz * vr[(b * LEVELS + l) * 2 + 1];
    const unsigned short* vbase = value + ((size_t)b * SLEN + START[l]) * DMODEL + h * DHEAD + d;
#pragma unroll
    for (int p = 0; p < 4; ++p) {
      const float offx = ob[l * 8 + p * 2 + 0];
      const float offy = ob[l * 8 + p * 2 + 1];
      const float x = (refx + offx / (float)W) * (float)W - 0.5f;
      const float y = (refy + offy / (float)H) * (float)H - 0.5f;
      const float x0f = floorf(x), y0f = floorf(y);
      const float fx = x - x0f, fy = y - y0f;
      const int x0 = (int)x0f, y0 = (int)y0f;
      float sv = 0.f;
#pragma unroll
      for (int ci = 0; ci < 4; ++ci) {
        const int xi = x0 + (ci & 1);
        const int yi = y0 + (ci >> 1);
        const float wx = (ci & 1) ? fx : (1.f - fx);
        const float wy = (ci >> 1) ? fy : (1.f - fy);
        if ((xi >= 0) && (xi < W) && (yi >= 0) && (yi < H))
          sv = fmaf(wx * wy, b2f(vbase[(size_t)(yi * W + xi) * DMODEL]), sv);
      }
      acc = fmaf(lv[l * 4 + p] * inv, sv, acc);
    }
  }
  outp[base * 256 + h * 32 + d] = f2b(acc);
}

// ---------------------------------------------------------------- LayerNorm (f32 in, f32 + bf16 out)
__global__ __launch_bounds__(256) void ln_k(const float* __restrict__ src,
                                            const float* __restrict__ w,
                                            const float* __restrict__ bias,
                                            float* __restrict__ dst,
                                            unsigned short* __restrict__ dstb) {
  const int row = blockIdx.x;
  const int tid = threadIdx.x;
  __shared__ float red[256];
  const float x = src[(size_t)row * DMODEL + tid];
  red[tid] = x;
  __syncthreads();
  for (int off = 128; off > 0; off >>= 1) {
    if (tid < off) red[tid] += red[tid + off];
    __syncthreads();
  }
  const float mu = red[0] * (1.f / DMODEL);
  __syncthreads();
  const float v = x - mu;
  red[tid] = v * v;
  __syncthreads();
  for (int off = 128; off > 0; off >>= 1) {
    if (tid < off) red[tid] += red[tid + off];
    __syncthreads();
  }
  const float var = red[0] * (1.f / DMODEL);
  const float y = v * rsqrtf(var + EPS_LN) * w[tid] + bias[tid];
  dst[(size_t)row * DMODEL + tid] = y;
  if (dstb) dstb[(size_t)row * DMODEL + tid] = f2b(y);
}

// ---------------------------------------------------------------- launcher
extern "C" void kernel_launch(void* const* d_in, const int* in_sizes, int n_in,
                              void* d_out, int out_size, void* d_ws, size_t ws_size,
                              hipStream_t stream) {
  const float* tgt     = (const float*)d_in[0];
  const float* refp    = (const float*)d_in[1];
  const float* src     = (const float*)d_in[2];
  const float* vr      = (const float*)d_in[3];
  const float* qpos    = (const float*)d_in[4];
  const float* sa_in_w = (const float*)d_in[5];
  const float* sa_in_b = (const float*)d_in[6];
  const float* sa_out_w= (const float*)d_in[7];
  const float* sa_out_b= (const float*)d_in[8];
  const float* samp_w  = (const float*)d_in[9];
  const float* samp_b  = (const float*)d_in[10];
  const float* attn_w  = (const float*)d_in[11];
  const float* attn_b  = (const float*)d_in[12];
  const float* val_w   = (const float*)d_in[13];
  const float* val_b   = (const float*)d_in[14];
  const float* ca_out_w= (const float*)d_in[15];
  const float* ca_out_b= (const float*)d_in[16];
  const float* ffn1_w  = (const float*)d_in[17];
  const float* ffn1_b  = (const float*)d_in[18];
  const float* ffn2_w  = (const float*)d_in[19];
  const float* ffn2_b  = (const float*)d_in[20];
  const float* ln1_w   = (const float*)d_in[21];
  const float* ln1_b   = (const float*)d_in[22];
  const float* ln2_w   = (const float*)d_in[23];
  const float* ln2_b   = (const float*)d_in[24];
  const float* ln3_w   = (const float*)d_in[25];
  const float* ln3_b   = (const float*)d_in[26];

  const int M = BS * NQ;                 // 3600
  const int MV = BS * SLEN;              // 78240
  const size_t TOK = (size_t)M * DMODEL; // 921600

  float* ws = (float*)d_ws;
  size_t off = 0;
  auto alloc = [&](size_t n) { float* p = ws + off; off += n; return p; };
  // f32 buffers
  float* cur   = alloc(TOK);
  float* qh    = alloc(TOK);
  float* kh    = alloc(TOK);
  float* vh    = alloc(TOK);
  float* tmp   = alloc(TOK);
  float* offb  = alloc(TOK);
  float* attl  = alloc((size_t)M * 128);
  // bf16 buffers (ushort, counted in floats/2)
  auto allocb = [&](size_t n) { unsigned short* p = (unsigned short*)(ws + off); off += (n + 1) / 2; return p; };
  unsigned short* cur_bf  = allocb(TOK);
  unsigned short* qbuf_bf = allocb(TOK);
  unsigned short* sao_bf  = allocb(TOK);
  unsigned short* msda_bf = allocb(TOK);
  unsigned short* ffnh_bf = allocb((size_t)M * DFF);
  unsigned short* src_bf  = allocb((size_t)MV * DMODEL);
  unsigned short* value_bf= allocb((size_t)MV * DMODEL);
  // bf16 weights
  unsigned short* w_in_bf   = allocb((size_t)NLAYERS * 768 * 256);
  unsigned short* w_saout_bf= allocb((size_t)NLAYERS * 256 * 256);
  unsigned short* w_samp_bf = allocb((size_t)NLAYERS * 256 * 256);
  unsigned short* w_attn_bf = allocb((size_t)NLAYERS * 128 * 256);
  unsigned short* w_val_bf  = allocb((size_t)NLAYERS * 256 * 256);
  unsigned short* w_caout_bf= allocb((size_t)NLAYERS * 256 * 256);
  unsigned short* w_ffn1_bf = allocb((size_t)NLAYERS * DFF * 256);
  unsigned short* w_ffn2_bf = allocb((size_t)NLAYERS * 256 * DFF);

  const int n4 = (int)(TOK / 4);
  const dim3 blk(256);
  const dim3 gE((n4 + 255) / 256);

  copycvt_k<<<gE, blk, 0, stream>>>(tgt, cur, cur_bf, n4);
  // one-time weight/src conversions
  f2b_k<<<dim3(2048), blk, 0, stream>>>(src, src_bf, MV * DMODEL / 4);
  f2b_k<<<dim3(1152), blk, 0, stream>>>(sa_in_w, w_in_bf, NLAYERS * 768 * 256 / 4);
  f2b_k<<<dim3(384), blk, 0, stream>>>(sa_out_w, w_saout_bf, NLAYERS * 256 * 256 / 4);
  f2b_k<<<dim3(384), blk, 0, stream>>>(samp_w, w_samp_bf, NLAYERS * 256 * 256 / 4);
  f2b_k<<<dim3(192), blk, 0, stream>>>(attn_w, w_attn_bf, NLAYERS * 128 * 256 / 4);
  f2b_k<<<dim3(384), blk, 0, stream>>>(val_w, w_val_bf, NLAYERS * 256 * 256 / 4);
  f2b_k<<<dim3(384), blk, 0, stream>>>(ca_out_w, w_caout_bf, NLAYERS * 256 * 256 / 4);
  f2b_k<<<dim3(1536), blk, 0, stream>>>(ffn1_w, w_ffn1_bf, NLAYERS * DFF * 256 / 4);
  f2b_k<<<dim3(1536), blk, 0, stream>>>(ffn2_w, w_ffn2_bf, NLAYERS * 256 * DFF / 4);

  const dim3 gT((M + 63) / 64, 256 / 64);   // N=256
  const dim3 gA((M + 63) / 64, 128 / 64);   // N=128
  const dim3 gF1((M + 63) / 64, DFF / 64);  // N=1024

  for (int l = 0; l < NLAYERS; ++l) {
    const unsigned short* wq = w_in_bf + (size_t)l * 768 * 256;
    const float* bq = sa_in_b + (size_t)l * 768;

    addcvt_k<<<gE, blk, 0, stream>>>(cur, qpos, qbuf_bf, n4);

    gemm_bf_k<<<gT, blk, 0, stream>>>(qbuf_bf, wq,            bq,       nullptr, qh, nullptr, M, 256, 256, 0);
    gemm_bf_k<<<gT, blk, 0, stream>>>(qbuf_bf, wq + 256*256,  bq + 256, nullptr, kh, nullptr, M, 256, 256, 0);
    gemm_bf_k<<<gT, blk, 0, stream>>>(cur_bf,  wq + 512*256,  bq + 512, nullptr, vh, nullptr, M, 256, 256, 0);

    fattn_k<<<dim3((NQ + QT - 1) / QT, HEADS, BS), blk, 0, stream>>>(qh, kh, vh, sao_bf);

    gemm_bf_k<<<gT, blk, 0, stream>>>(sao_bf, w_saout_bf + (size_t)l * 256 * 256,
                                      sa_out_b + l * 256, cur, tmp, nullptr, M, 256, 256, 0);
    ln_k<<<dim3(M), blk, 0, stream>>>(tmp, ln1_w + l * 256, ln1_b + l * 256, cur, cur_bf);

    // cross-attn (MSDA)
    addcvt_k<<<gE, blk, 0, stream>>>(cur, qpos, qbuf_bf, n4);

    gemm_vmfma_k<<<dim3((MV + 127) / 128, 2), blk, 0, stream>>>(
        src_bf, w_val_bf + (size_t)l * 256 * 256, val_b + l * 256, value_bf, MV);
    gemm_bf_k<<<gT, blk, 0, stream>>>(qbuf_bf, w_samp_bf + (size_t)l * 256 * 256,
                                      samp_b + l * 256, nullptr, offb, nullptr, M, 256, 256, 0);
    gemm_bf_k<<<gA, blk, 0, stream>>>(qbuf_bf, w_attn_bf + (size_t)l * 128 * 256,
                                      attn_b + l * 128, nullptr, attl, nullptr, M, 128, 256, 0);

    msda_k<<<dim3(NQ, BS), blk, 0, stream>>>(refp, vr, value_bf, offb, attl, msda_bf);

    gemm_bf_k<<<gT, blk, 0, stream>>>(msda_bf, w_caout_bf + (size_t)l * 256 * 256,
                                      ca_out_b + l * 256, cur, tmp, nullptr, M, 256, 256, 0);
    ln_k<<<dim3(M), blk, 0, stream>>>(tmp, ln2_w + l * 256, ln2_b + l * 256, cur, cur_bf);

    // FFN
    gemm_bf_k<<<gF1, blk, 0, stream>>>(cur_bf, w_ffn1_bf + (size_t)l * DFF * 256,
                                       ffn1_b + l * DFF, nullptr, nullptr, ffnh_bf, M, DFF, 256, 1);
    gemm_bf_k<<<gT, blk, 0, stream>>>(ffnh_bf, w_ffn2_bf + (size_t)l * 256 * DFF,
                                      ffn2_b + l * 256, cur, tmp, nullptr, M, 256, DFF, 0);
    ln_k<<<dim3(M), blk, 0, stream>>>(tmp, ln3_w + l * 256, ln3_b + l * 256, cur,
                                      (l == NLAYERS - 1) ? nullptr : cur_bf);
  }

  copy_k<<<gE, blk, 0, stream>>>(cur, (float*)d_out, n4);
}

// Round 4
// 1665.905 us; speedup vs baseline: 4.2887x; 1.2902x over previous
//
#include <hip/hip_runtime.h>
#include <math.h>

#define DMODEL 256
#define HEADS 8
#define DHEAD 32
#define LEVELS 4
#define POINTS 4
#define NLAYERS 6
#define DFF 1024
#define BS 4
#define NQ 900
#define SLEN 19560
#define EPS_LN 1e-5f
#define ATT_SCALE 0.17677669529663689f

typedef __attribute__((ext_vector_type(8))) short bf16x8;
typedef __attribute__((ext_vector_type(4))) float f32x4;
typedef __attribute__((ext_vector_type(4))) unsigned short u16x4;
typedef __attribute__((ext_vector_type(8))) unsigned short u16x8;

__device__ __forceinline__ unsigned short f2b(float x) {
  unsigned u = __float_as_uint(x);
  u += 0x7FFF + ((u >> 16) & 1);
  return (unsigned short)(u >> 16);
}
__device__ __forceinline__ float b2f(unsigned short v) {
  return __uint_as_float(((unsigned)v) << 16);
}

// ---------------------------------------------------------------- elementwise
// cur=tgt (f32), cur_bf=bf16(tgt), qbuf_bf=bf16(tgt+qpos)
__global__ __launch_bounds__(256) void copycvt_k(const float* __restrict__ a,
                                                 const float* __restrict__ qp,
                                                 float* __restrict__ cf,
                                                 unsigned short* __restrict__ cb,
                                                 unsigned short* __restrict__ qb, int n4) {
  int i = blockIdx.x * 256 + threadIdx.x;
  if (i < n4) {
    float4 v = reinterpret_cast<const float4*>(a)[i];
    float4 q = reinterpret_cast<const float4*>(qp)[i];
    reinterpret_cast<float4*>(cf)[i] = v;
    u16x4 o4 = {f2b(v.x), f2b(v.y), f2b(v.z), f2b(v.w)};
    reinterpret_cast<u16x4*>(cb)[i] = o4;
    u16x4 p4 = {f2b(v.x + q.x), f2b(v.y + q.y), f2b(v.z + q.z), f2b(v.w + q.w)};
    reinterpret_cast<u16x4*>(qb)[i] = p4;
  }
}

__global__ __launch_bounds__(256) void copy_k(const float* __restrict__ a,
                                              float* __restrict__ c, int n4) {
  int i = blockIdx.x * 256 + threadIdx.x;
  if (i < n4) reinterpret_cast<float4*>(c)[i] = reinterpret_cast<const float4*>(a)[i];
}

__global__ __launch_bounds__(256) void f2b_k(const float* __restrict__ in,
                                             unsigned short* __restrict__ out, int n4) {
  for (int i = blockIdx.x * 256 + threadIdx.x; i < n4; i += gridDim.x * 256) {
    float4 v = reinterpret_cast<const float4*>(in)[i];
    u16x4 o4 = {f2b(v.x), f2b(v.y), f2b(v.z), f2b(v.w)};
    reinterpret_cast<u16x4*>(out)[i] = o4;
  }
}

// concat samp_w(256x256)+attn_w(128x256) -> [NLAYERS][384][256] bf16, biases -> f32
__global__ __launch_bounds__(256) void catw_k(const float* __restrict__ sw,
                                              const float* __restrict__ aw,
                                              const float* __restrict__ sb,
                                              const float* __restrict__ ab,
                                              unsigned short* __restrict__ wout,
                                              float* __restrict__ bout) {
  int i = blockIdx.x * 256 + threadIdx.x;
  const int total4 = NLAYERS * 384 * 256 / 4;
  if (i < total4) {
    int l = i / (384 * 64);
    int r = i % (384 * 64);
    int row = r / 64;
    int c4 = r % 64;
    const float* srcp = row < 256
        ? sw + ((size_t)l * 256 * 256 + (size_t)row * 256 + c4 * 4)
        : aw + ((size_t)l * 128 * 256 + (size_t)(row - 256) * 256 + c4 * 4);
    float4 v = *(const float4*)srcp;
    u16x4 o4 = {f2b(v.x), f2b(v.y), f2b(v.z), f2b(v.w)};
    *(u16x4*)(wout + (size_t)i * 4) = o4;
  }
  if (i < NLAYERS * 384) {
    int l = i / 384, r = i % 384;
    bout[i] = r < 256 ? sb[l * 256 + r] : ab[l * 128 + (r - 256)];
  }
}

// ---------------------------------------------------------------- bf16 MFMA GEMM, 64x64 tile
// out[M,N] (ld=ldo) = A_bf[M,K] @ W_bf[N,K]^T + bias; optional f32 res (ld=ldo); relu;
// writes outf (f32) and/or outb (bf16). N,K multiples of 64.
__global__ __launch_bounds__(256) void gemm_bf_k(const unsigned short* __restrict__ A,
                                                 const unsigned short* __restrict__ W,
                                                 const float* __restrict__ bias,
                                                 const float* __restrict__ res,
                                                 float* __restrict__ outf,
                                                 unsigned short* __restrict__ outb,
                                                 int ldo, int M, int N, int K, int relu) {
  __shared__ unsigned short As[64][72];
  __shared__ unsigned short Ws[64][72];
  const int tid = threadIdx.x;
  const int lane = tid & 63, wv = tid >> 6;
  const int wm = wv >> 1, wn = wv & 1;
  const int m0 = blockIdx.x * 64, n0 = blockIdx.y * 64;
  const int l15 = lane & 15, l4 = lane >> 4;

  f32x4 acc[2][2] = {};
  for (int k0 = 0; k0 < K; k0 += 64) {
#pragma unroll
    for (int t = 0; t < 2; ++t) {
      int u = t * 256 + tid;
      int r = u >> 3, c8 = u & 7;
      int ra = m0 + r; if (ra >= M) ra = M - 1;
      *(u16x8*)&As[r][c8 * 8] = *(const u16x8*)(A + (size_t)ra * K + k0 + c8 * 8);
      *(u16x8*)&Ws[r][c8 * 8] = *(const u16x8*)(W + (size_t)(n0 + r) * K + k0 + c8 * 8);
    }
    __syncthreads();
#pragma unroll
    for (int ks = 0; ks < 64; ks += 32) {
      bf16x8 af[2], wf[2];
#pragma unroll
      for (int fr = 0; fr < 2; ++fr)
        af[fr] = *(const bf16x8*)&As[wm * 32 + fr * 16 + l15][ks + l4 * 8];
#pragma unroll
      for (int fn = 0; fn < 2; ++fn)
        wf[fn] = *(const bf16x8*)&Ws[wn * 32 + fn * 16 + l15][ks + l4 * 8];
#pragma unroll
      for (int fr = 0; fr < 2; ++fr)
#pragma unroll
        for (int fn = 0; fn < 2; ++fn)
          acc[fr][fn] = __builtin_amdgcn_mfma_f32_16x16x32_bf16(
              af[fr], wf[fn], acc[fr][fn], 0, 0, 0);
    }
    __syncthreads();
  }
#pragma unroll
  for (int fr = 0; fr < 2; ++fr)
#pragma unroll
    for (int fn = 0; fn < 2; ++fn) {
      int col = n0 + wn * 32 + fn * 16 + l15;
      float bs = bias[col];
#pragma unroll
      for (int j = 0; j < 4; ++j) {
        int row = m0 + wm * 32 + fr * 16 + l4 * 4 + j;
        if (row >= M) continue;
        float v = acc[fr][fn][j] + bs;
        if (res) v += res[(size_t)row * ldo + col];
        if (relu) v = fmaxf(v, 0.f);
        if (outf) outf[(size_t)row * ldo + col] = v;
        if (outb) outb[(size_t)row * ldo + col] = f2b(v);
      }
    }
}

// ---------------------------------------------------------------- bf16 MFMA GEMM (value proj, 128x128)
__global__ __launch_bounds__(256) void gemm_vmfma_k(const unsigned short* __restrict__ A,
                                                    const unsigned short* __restrict__ W,
                                                    const float* __restrict__ bias,
                                                    unsigned short* __restrict__ C,
                                                    int M) {
  __shared__ unsigned short As[128][72];
  __shared__ unsigned short Ws[128][72];
  const int tid = threadIdx.x;
  const int lane = tid & 63, wv = tid >> 6;
  const int wm = wv >> 1, wn = wv & 1;
  const int m0 = blockIdx.x * 128, n0 = blockIdx.y * 128;
  const int l15 = lane & 15, l4 = lane >> 4;

  f32x4 acc[4][4] = {};

  for (int k0 = 0; k0 < 256; k0 += 64) {
#pragma unroll
    for (int t = 0; t < 4; ++t) {
      int u = t * 256 + tid;
      int r = u >> 3, c8 = u & 7;
      int ra = m0 + r; if (ra >= M) ra = M - 1;
      *(u16x8*)&As[r][c8 * 8] = *(const u16x8*)(A + (size_t)ra * 256 + k0 + c8 * 8);
      *(u16x8*)&Ws[r][c8 * 8] = *(const u16x8*)(W + (size_t)(n0 + r) * 256 + k0 + c8 * 8);
    }
    __syncthreads();
#pragma unroll
    for (int ks = 0; ks < 64; ks += 32) {
      bf16x8 af[4], bf[4];
#pragma unroll
      for (int fr = 0; fr < 4; ++fr)
        af[fr] = *(const bf16x8*)&As[wm * 64 + fr * 16 + l15][ks + l4 * 8];
#pragma unroll
      for (int fn = 0; fn < 4; ++fn)
        bf[fn] = *(const bf16x8*)&Ws[wn * 64 + fn * 16 + l15][ks + l4 * 8];
#pragma unroll
      for (int fr = 0; fr < 4; ++fr)
#pragma unroll
        for (int fn = 0; fn < 4; ++fn)
          acc[fr][fn] = __builtin_amdgcn_mfma_f32_16x16x32_bf16(
              af[fr], bf[fn], acc[fr][fn], 0, 0, 0);
    }
    __syncthreads();
  }
#pragma unroll
  for (int fr = 0; fr < 4; ++fr)
#pragma unroll
    for (int fn = 0; fn < 4; ++fn) {
      int col = n0 + wn * 64 + fn * 16 + l15;
      float bs = bias[col];
#pragma unroll
      for (int j = 0; j < 4; ++j) {
        int row = m0 + wm * 64 + fr * 16 + l4 * 4 + j;
        if (row < M) C[(size_t)row * 256 + col] = f2b(acc[fr][fn][j] + bs);
      }
    }
}

// ---------------------------------------------------------------- MFMA flash self-attn
// qkv: [B*NQ][768] bf16 (q|k|v). o: [B*NQ][256] bf16.
// grid (15, HEADS, BS), 256 thr = 4 waves; wave w owns query rows w*16..+16.
__global__ __launch_bounds__(256) void fattn_mfma_k(const unsigned short* __restrict__ qkv,
                                                    unsigned short* __restrict__ o) {
  __shared__ unsigned short Qlds[64][40];
  __shared__ unsigned short Klds[64][40];
  __shared__ unsigned short Vt[32][72];   // V transposed [dh][key]
  __shared__ unsigned short Plds[64][72];
  const int tid = threadIdx.x;
  const int lane = tid & 63;
  const int wq = tid >> 6;
  const int l15 = lane & 15, l4 = lane >> 4;
  const int q0 = blockIdx.x * 64;
  const int h = blockIdx.y, b = blockIdx.z;
  const int hq = h * 32;
  const size_t rowb = (size_t)b * NQ;

  {
    int q = q0 + (tid >> 2);
    int qc = q < NQ ? q : NQ - 1;
    *(u16x8*)&Qlds[tid >> 2][(tid & 3) * 8] =
        *(const u16x8*)(qkv + (rowb + qc) * 768 + hq + (tid & 3) * 8);
  }
  __syncthreads();
  const bf16x8 qf = *(const bf16x8*)&Qlds[wq * 16 + l15][l4 * 8];

  float m_r[4] = {-1e30f, -1e30f, -1e30f, -1e30f};
  float l_r[4] = {0.f, 0.f, 0.f, 0.f};
  f32x4 oacc[2] = {};

  for (int k0 = 0; k0 < NQ; k0 += 64) {
    __syncthreads();
    {
      int kk = k0 + (tid >> 2);
      int kc = kk < NQ ? kk : NQ - 1;
      const unsigned short* kbase = qkv + (rowb + kc) * 768 + hq + (tid & 3) * 8;
      u16x8 kv = *(const u16x8*)(kbase + 256);
      u16x8 vv = *(const u16x8*)(kbase + 512);
      *(u16x8*)&Klds[tid >> 2][(tid & 3) * 8] = kv;
#pragma unroll
      for (int i = 0; i < 8; ++i) Vt[(tid & 3) * 8 + i][tid >> 2] = vv[i];
    }
    __syncthreads();

    // S = Q K^T  (row = query l4*4+j, col = key fc*16+l15)
    f32x4 s[4];
#pragma unroll
    for (int fc = 0; fc < 4; ++fc) {
      bf16x8 kf = *(const bf16x8*)&Klds[fc * 16 + l15][l4 * 8];
      s[fc] = __builtin_amdgcn_mfma_f32_16x16x32_bf16(qf, kf, (f32x4){0.f, 0.f, 0.f, 0.f}, 0, 0, 0);
    }
#pragma unroll
    for (int fc = 0; fc < 4; ++fc) {
      bool oob = (k0 + fc * 16 + l15) >= NQ;
#pragma unroll
      for (int j = 0; j < 4; ++j)
        s[fc][j] = oob ? -1e30f : s[fc][j] * ATT_SCALE;
    }
    // online softmax per row j
#pragma unroll
    for (int j = 0; j < 4; ++j) {
      float tm = fmaxf(fmaxf(s[0][j], s[1][j]), fmaxf(s[2][j], s[3][j]));
      tm = fmaxf(tm, __shfl_xor(tm, 1, 16));
      tm = fmaxf(tm, __shfl_xor(tm, 2, 16));
      tm = fmaxf(tm, __shfl_xor(tm, 4, 16));
      tm = fmaxf(tm, __shfl_xor(tm, 8, 16));
      float mn = fmaxf(m_r[j], tm);
      float sf = __expf(m_r[j] - mn);
      m_r[j] = mn;
      oacc[0][j] *= sf;
      oacc[1][j] *= sf;
      float rs = 0.f;
#pragma unroll
      for (int fc = 0; fc < 4; ++fc) {
        float pv = __expf(s[fc][j] - mn);
        s[fc][j] = pv;
        rs += pv;
      }
      rs += __shfl_xor(rs, 1, 16);
      rs += __shfl_xor(rs, 2, 16);
      rs += __shfl_xor(rs, 4, 16);
      rs += __shfl_xor(rs, 8, 16);
      l_r[j] = l_r[j] * sf + rs;
    }
    // P -> LDS (bf16)
#pragma unroll
    for (int fc = 0; fc < 4; ++fc)
#pragma unroll
      for (int j = 0; j < 4; ++j)
        Plds[wq * 16 + l4 * 4 + j][fc * 16 + l15] = f2b(s[fc][j]);
    __syncthreads();
    // O += P V
#pragma unroll
    for (int ks = 0; ks < 2; ++ks) {
      bf16x8 pf = *(const bf16x8*)&Plds[wq * 16 + l15][ks * 32 + l4 * 8];
#pragma unroll
      for (int oc = 0; oc < 2; ++oc) {
        bf16x8 vf = *(const bf16x8*)&Vt[oc * 16 + l15][ks * 32 + l4 * 8];
        oacc[oc] = __builtin_amdgcn_mfma_f32_16x16x32_bf16(pf, vf, oacc[oc], 0, 0, 0);
      }
    }
  }
#pragma unroll
  for (int j = 0; j < 4; ++j) {
    int q = q0 + wq * 16 + l4 * 4 + j;
    if (q < NQ) {
      float inv = 1.f / l_r[j];
      o[(rowb + q) * 256 + hq + l15] = f2b(oacc[0][j] * inv);
      o[(rowb + q) * 256 + hq + 16 + l15] = f2b(oacc[1][j] * inv);
    }
  }
}

// ---------------------------------------------------------------- MSDA sample (bf16 value)
// cat: [M][384] f32 — cols 0..255 = sampling offsets, 256..383 = attn logits
__global__ __launch_bounds__(256) void msda_k(const float* __restrict__ refp,
                                              const float* __restrict__ vr,
                                              const unsigned short* __restrict__ value,
                                              const float* __restrict__ cat,
                                              unsigned short* __restrict__ outp) {
  const int HW[4][2] = {{92, 160}, {46, 80}, {23, 40}, {12, 20}};
  const int START[4] = {0, 14720, 18400, 19320};
  const int qi = blockIdx.x, b = blockIdx.y;
  const int tid = threadIdx.x;
  const int h = tid >> 5, d = tid & 31;
  const size_t base = (size_t)(b * NQ + qi);
  const float rx = refp[base * 3 + 0];
  const float rz = refp[base * 3 + 2];

  const float* lg = cat + base * 384 + 256 + h * 16;
  float lv[16];
  float mx = -1e30f;
#pragma unroll
  for (int j = 0; j < 16; ++j) { lv[j] = lg[j]; mx = fmaxf(mx, lv[j]); }
  float sum = 0.f;
#pragma unroll
  for (int j = 0; j < 16; ++j) { lv[j] = __expf(lv[j] - mx); sum += lv[j]; }
  const float inv = 1.f / sum;

  const float* ob = cat + base * 384 + h * 32;
  float acc = 0.f;
#pragma unroll
  for (int l = 0; l < 4; ++l) {
    const int H = HW[l][0], W = HW[l][1];
    const float refx = rx * vr[(b * LEVELS + l) * 2 + 0];
    const float refy = rz * vr[(b * LEVELS + l) * 2 + 1];
    const unsigned short* vbase = value + ((size_t)b * SLEN + START[l]) * DMODEL + h * DHEAD + d;
#pragma unroll
    for (int p = 0; p < 4; ++p) {
      const float offx = ob[l * 8 + p * 2 + 0];
      const float offy = ob[l * 8 + p * 2 + 1];
      const float x = (refx + offx / (float)W) * (float)W - 0.5f;
      const float y = (refy + offy / (float)H) * (float)H - 0.5f;
      const float x0f = floorf(x), y0f = floorf(y);
      const float fx = x - x0f, fy = y - y0f;
      const int x0 = (int)x0f, y0 = (int)y0f;
      float sv = 0.f;
#pragma unroll
      for (int ci = 0; ci < 4; ++ci) {
        const int xi = x0 + (ci & 1);
        const int yi = y0 + (ci >> 1);
        const float wx = (ci & 1) ? fx : (1.f - fx);
        const float wy = (ci >> 1) ? fy : (1.f - fy);
        if ((xi >= 0) && (xi < W) && (yi >= 0) && (yi < H))
          sv = fmaf(wx * wy, b2f(vbase[(size_t)(yi * W + xi) * DMODEL]), sv);
      }
      acc = fmaf(lv[l * 4 + p] * inv, sv, acc);
    }
  }
  outp[base * 256 + h * 32 + d] = f2b(acc);
}

// ---------------------------------------------------------------- LayerNorm (f32 in; f32 out + optional bf16 + optional (y+qpos) bf16)
__global__ __launch_bounds__(256) void ln_k(const float* __restrict__ src,
                                            const float* __restrict__ w,
                                            const float* __restrict__ bias,
                                            const float* __restrict__ qpos,
                                            float* __restrict__ dst,
                                            unsigned short* __restrict__ dstb,
                                            unsigned short* __restrict__ qposb) {
  const int row = blockIdx.x;
  const int tid = threadIdx.x;
  __shared__ float red[256];
  const float x = src[(size_t)row * DMODEL + tid];
  red[tid] = x;
  __syncthreads();
  for (int off = 128; off > 0; off >>= 1) {
    if (tid < off) red[tid] += red[tid + off];
    __syncthreads();
  }
  const float mu = red[0] * (1.f / DMODEL);
  __syncthreads();
  const float v = x - mu;
  red[tid] = v * v;
  __syncthreads();
  for (int off = 128; off > 0; off >>= 1) {
    if (tid < off) red[tid] += red[tid + off];
    __syncthreads();
  }
  const float var = red[0] * (1.f / DMODEL);
  const float y = v * rsqrtf(var + EPS_LN) * w[tid] + bias[tid];
  dst[(size_t)row * DMODEL + tid] = y;
  if (dstb) dstb[(size_t)row * DMODEL + tid] = f2b(y);
  if (qposb) qposb[(size_t)row * DMODEL + tid] = f2b(y + qpos[(size_t)row * DMODEL + tid]);
}

// ---------------------------------------------------------------- launcher
extern "C" void kernel_launch(void* const* d_in, const int* in_sizes, int n_in,
                              void* d_out, int out_size, void* d_ws, size_t ws_size,
                              hipStream_t stream) {
  const float* tgt     = (const float*)d_in[0];
  const float* refp    = (const float*)d_in[1];
  const float* src     = (const float*)d_in[2];
  const float* vr      = (const float*)d_in[3];
  const float* qpos    = (const float*)d_in[4];
  const float* sa_in_w = (const float*)d_in[5];
  const float* sa_in_b = (const float*)d_in[6];
  const float* sa_out_w= (const float*)d_in[7];
  const float* sa_out_b= (const float*)d_in[8];
  const float* samp_w  = (const float*)d_in[9];
  const float* samp_b  = (const float*)d_in[10];
  const float* attn_w  = (const float*)d_in[11];
  const float* attn_b  = (const float*)d_in[12];
  const float* val_w   = (const float*)d_in[13];
  const float* val_b   = (const float*)d_in[14];
  const float* ca_out_w= (const float*)d_in[15];
  const float* ca_out_b= (const float*)d_in[16];
  const float* ffn1_w  = (const float*)d_in[17];
  const float* ffn1_b  = (const float*)d_in[18];
  const float* ffn2_w  = (const float*)d_in[19];
  const float* ffn2_b  = (const float*)d_in[20];
  const float* ln1_w   = (const float*)d_in[21];
  const float* ln1_b   = (const float*)d_in[22];
  const float* ln2_w   = (const float*)d_in[23];
  const float* ln2_b   = (const float*)d_in[24];
  const float* ln3_w   = (const float*)d_in[25];
  const float* ln3_b   = (const float*)d_in[26];

  const int M = BS * NQ;                 // 3600
  const int MV = BS * SLEN;              // 78240
  const size_t TOK = (size_t)M * DMODEL; // 921600

  float* ws = (float*)d_ws;
  size_t off = 0;
  auto alloc = [&](size_t n) { float* p = ws + off; off += n; return p; };
  auto allocb = [&](size_t n) { unsigned short* p = (unsigned short*)(ws + off); off += (n + 1) / 2; return p; };
  float* cur    = alloc(TOK);
  float* tmp    = alloc(TOK);
  float* catout = alloc((size_t)M * 384);
  float* b_cacat= alloc((size_t)NLAYERS * 384);
  unsigned short* cur_bf  = allocb(TOK);
  unsigned short* qbuf_bf = allocb(TOK);
  unsigned short* sao_bf  = allocb(TOK);
  unsigned short* msda_bf = allocb(TOK);
  unsigned short* qkv_bf  = allocb((size_t)M * 768);
  unsigned short* ffnh_bf = allocb((size_t)M * DFF);
  unsigned short* src_bf  = allocb((size_t)MV * DMODEL);
  unsigned short* value_bf= allocb((size_t)MV * DMODEL);
  unsigned short* w_in_bf   = allocb((size_t)NLAYERS * 768 * 256);
  unsigned short* w_saout_bf= allocb((size_t)NLAYERS * 256 * 256);
  unsigned short* w_cacat_bf= allocb((size_t)NLAYERS * 384 * 256);
  unsigned short* w_val_bf  = allocb((size_t)NLAYERS * 256 * 256);
  unsigned short* w_caout_bf= allocb((size_t)NLAYERS * 256 * 256);
  unsigned short* w_ffn1_bf = allocb((size_t)NLAYERS * DFF * 256);
  unsigned short* w_ffn2_bf = allocb((size_t)NLAYERS * 256 * DFF);

  const int n4 = (int)(TOK / 4);
  const dim3 blk(256);
  const dim3 gE((n4 + 255) / 256);

  copycvt_k<<<gE, blk, 0, stream>>>(tgt, qpos, cur, cur_bf, qbuf_bf, n4);
  f2b_k<<<dim3(2048), blk, 0, stream>>>(src, src_bf, MV * DMODEL / 4);
  f2b_k<<<dim3(1152), blk, 0, stream>>>(sa_in_w, w_in_bf, NLAYERS * 768 * 256 / 4);
  f2b_k<<<dim3(384), blk, 0, stream>>>(sa_out_w, w_saout_bf, NLAYERS * 256 * 256 / 4);
  f2b_k<<<dim3(384), blk, 0, stream>>>(val_w, w_val_bf, NLAYERS * 256 * 256 / 4);
  f2b_k<<<dim3(384), blk, 0, stream>>>(ca_out_w, w_caout_bf, NLAYERS * 256 * 256 / 4);
  f2b_k<<<dim3(1536), blk, 0, stream>>>(ffn1_w, w_ffn1_bf, NLAYERS * DFF * 256 / 4);
  f2b_k<<<dim3(1536), blk, 0, stream>>>(ffn2_w, w_ffn2_bf, NLAYERS * 256 * DFF / 4);
  catw_k<<<dim3(576), blk, 0, stream>>>(samp_w, attn_w, samp_b, attn_b, w_cacat_bf, b_cacat);

  const dim3 gQK((M + 63) / 64, 512 / 64);
  const dim3 gV((M + 63) / 64, 256 / 64);
  const dim3 gN256((M + 63) / 64, 256 / 64);
  const dim3 gCat((M + 63) / 64, 384 / 64);
  const dim3 gF1((M + 63) / 64, DFF / 64);

  for (int l = 0; l < NLAYERS; ++l) {
    const unsigned short* wq = w_in_bf + (size_t)l * 768 * 256;
    const float* bq = sa_in_b + (size_t)l * 768;

    // QKV projections -> qkv_bf [M][768]
    gemm_bf_k<<<gQK, blk, 0, stream>>>(qbuf_bf, wq, bq, nullptr,
                                       nullptr, qkv_bf, 768, M, 512, 256, 0);
    gemm_bf_k<<<gV, blk, 0, stream>>>(cur_bf, wq + 512 * 256, bq + 512, nullptr,
                                      nullptr, qkv_bf + 512, 768, M, 256, 256, 0);

    fattn_mfma_k<<<dim3((NQ + 63) / 64, HEADS, BS), blk, 0, stream>>>(qkv_bf, sao_bf);

    gemm_bf_k<<<gN256, blk, 0, stream>>>(sao_bf, w_saout_bf + (size_t)l * 256 * 256,
                                         sa_out_b + l * 256, cur, tmp, nullptr, 256, M, 256, 256, 0);
    ln_k<<<dim3(M), blk, 0, stream>>>(tmp, ln1_w + l * 256, ln1_b + l * 256, qpos,
                                      cur, nullptr, qbuf_bf);

    // cross-attn (MSDA)
    gemm_vmfma_k<<<dim3((MV + 127) / 128, 2), blk, 0, stream>>>(
        src_bf, w_val_bf + (size_t)l * 256 * 256, val_b + l * 256, value_bf, MV);
    gemm_bf_k<<<gCat, blk, 0, stream>>>(qbuf_bf, w_cacat_bf + (size_t)l * 384 * 256,
                                        b_cacat + l * 384, nullptr, catout, nullptr, 384, M, 384, 256, 0);

    msda_k<<<dim3(NQ, BS), blk, 0, stream>>>(refp, vr, value_bf, catout, msda_bf);

    gemm_bf_k<<<gN256, blk, 0, stream>>>(msda_bf, w_caout_bf + (size_t)l * 256 * 256,
                                         ca_out_b + l * 256, cur, tmp, nullptr, 256, M, 256, 256, 0);
    ln_k<<<dim3(M), blk, 0, stream>>>(tmp, ln2_w + l * 256, ln2_b + l * 256, nullptr,
                                      cur, cur_bf, nullptr);

    // FFN
    gemm_bf_k<<<gF1, blk, 0, stream>>>(cur_bf, w_ffn1_bf + (size_t)l * DFF * 256,
                                       ffn1_b + l * DFF, nullptr, nullptr, ffnh_bf, DFF, M, DFF, 256, 1);
    gemm_bf_k<<<gN256, blk, 0, stream>>>(ffnh_bf, w_ffn2_bf + (size_t)l * 256 * DFF,
                                         ffn2_b + l * 256, cur, tmp, nullptr, 256, M, 256, DFF, 0);
    const bool last = (l == NLAYERS - 1);
    ln_k<<<dim3(M), blk, 0, stream>>>(tmp, ln3_w + l * 256, ln3_b + l * 256,
                                      last ? nullptr : qpos, cur,
                                      last ? nullptr : cur_bf,
                                      last ? nullptr : qbuf_bf);
  }

  copy_k<<<gE, blk, 0, stream>>>(cur, (float*)d_out, n4);
}

// Round 5
// 1398.913 us; speedup vs baseline: 5.1073x; 1.1909x over previous
//
#include <hip/hip_runtime.h>
#include <math.h>

#define DMODEL 256
#define HEADS 8
#define DHEAD 32
#define LEVELS 4
#define POINTS 4
#define NLAYERS 6
#define DFF 1024
#define BS 4
#define NQ 900
#define SLEN 19560
#define EPS_LN 1e-5f
#define ATT_SCALE 0.17677669529663689f

typedef __attribute__((ext_vector_type(8))) short bf16x8;
typedef __attribute__((ext_vector_type(4))) float f32x4;
typedef __attribute__((ext_vector_type(4))) unsigned short u16x4;
typedef __attribute__((ext_vector_type(8))) unsigned short u16x8;

__device__ __forceinline__ unsigned short f2b(float x) {
  unsigned u = __float_as_uint(x);
  u += 0x7FFF + ((u >> 16) & 1);
  return (unsigned short)(u >> 16);
}
__device__ __forceinline__ float b2f(unsigned short v) {
  return __uint_as_float(((unsigned)v) << 16);
}

// ---------------------------------------------------------------- elementwise
// cur=tgt (f32), cur_bf=bf16(tgt), qbuf_bf=bf16(tgt+qpos)
__global__ __launch_bounds__(256) void copycvt_k(const float* __restrict__ a,
                                                 const float* __restrict__ qp,
                                                 float* __restrict__ cf,
                                                 unsigned short* __restrict__ cb,
                                                 unsigned short* __restrict__ qb, int n4) {
  int i = blockIdx.x * 256 + threadIdx.x;
  if (i < n4) {
    float4 v = reinterpret_cast<const float4*>(a)[i];
    float4 q = reinterpret_cast<const float4*>(qp)[i];
    reinterpret_cast<float4*>(cf)[i] = v;
    u16x4 o4 = {f2b(v.x), f2b(v.y), f2b(v.z), f2b(v.w)};
    reinterpret_cast<u16x4*>(cb)[i] = o4;
    u16x4 p4 = {f2b(v.x + q.x), f2b(v.y + q.y), f2b(v.z + q.z), f2b(v.w + q.w)};
    reinterpret_cast<u16x4*>(qb)[i] = p4;
  }
}

// fused bf16 conversion of src + 6 weight tensors
#define N4_SRC (SLEN * BS * DMODEL / 4)
#define N4_SAIN (NLAYERS * 768 * 256 / 4)
#define N4_SQ (NLAYERS * 256 * 256 / 4)
#define N4_FFN (NLAYERS * DFF * 256 / 4)
__global__ __launch_bounds__(256) void f2ball_k(
    const float* __restrict__ s0, const float* __restrict__ s1,
    const float* __restrict__ s2, const float* __restrict__ s3,
    const float* __restrict__ s4, const float* __restrict__ s5,
    const float* __restrict__ s6,
    unsigned short* __restrict__ d0, unsigned short* __restrict__ d1,
    unsigned short* __restrict__ d2, unsigned short* __restrict__ d3,
    unsigned short* __restrict__ d4, unsigned short* __restrict__ d5,
    unsigned short* __restrict__ d6) {
  const int total = N4_SRC + N4_SAIN + 3 * N4_SQ + 2 * N4_FFN;
  for (int i = blockIdx.x * 256 + threadIdx.x; i < total; i += gridDim.x * 256) {
    const float* s;
    unsigned short* d;
    int j = i;
    if (j < N4_SRC) { s = s0; d = d0; }
    else { j -= N4_SRC;
      if (j < N4_SAIN) { s = s1; d = d1; }
      else { j -= N4_SAIN;
        if (j < N4_SQ) { s = s2; d = d2; }
        else { j -= N4_SQ;
          if (j < N4_SQ) { s = s3; d = d3; }
          else { j -= N4_SQ;
            if (j < N4_SQ) { s = s4; d = d4; }
            else { j -= N4_SQ;
              if (j < N4_FFN) { s = s5; d = d5; }
              else { j -= N4_FFN; s = s6; d = d6; } } } } } }
    float4 v = reinterpret_cast<const float4*>(s)[j];
    u16x4 o4 = {f2b(v.x), f2b(v.y), f2b(v.z), f2b(v.w)};
    reinterpret_cast<u16x4*>(d)[j] = o4;
  }
}

// concat samp_w(256x256)+attn_w(128x256) -> [NLAYERS][384][256] bf16, biases -> f32
__global__ __launch_bounds__(256) void catw_k(const float* __restrict__ sw,
                                              const float* __restrict__ aw,
                                              const float* __restrict__ sb,
                                              const float* __restrict__ ab,
                                              unsigned short* __restrict__ wout,
                                              float* __restrict__ bout) {
  int i = blockIdx.x * 256 + threadIdx.x;
  const int total4 = NLAYERS * 384 * 256 / 4;
  if (i < total4) {
    int l = i / (384 * 64);
    int r = i % (384 * 64);
    int row = r / 64;
    int c4 = r % 64;
    const float* srcp = row < 256
        ? sw + ((size_t)l * 256 * 256 + (size_t)row * 256 + c4 * 4)
        : aw + ((size_t)l * 128 * 256 + (size_t)(row - 256) * 256 + c4 * 4);
    float4 v = *(const float4*)srcp;
    u16x4 o4 = {f2b(v.x), f2b(v.y), f2b(v.z), f2b(v.w)};
    *(u16x4*)(wout + (size_t)i * 4) = o4;
  }
  if (i < NLAYERS * 384) {
    int l = i / 384, r = i % 384;
    bout[i] = r < 256 ? sb[l * 256 + r] : ab[l * 128 + (r - 256)];
  }
}

// ---------------------------------------------------------------- bf16 MFMA GEMM, 64x64 tile
__global__ __launch_bounds__(256) void gemm_bf_k(const unsigned short* __restrict__ A,
                                                 const unsigned short* __restrict__ W,
                                                 const float* __restrict__ bias,
                                                 const float* __restrict__ res,
                                                 float* __restrict__ outf,
                                                 unsigned short* __restrict__ outb,
                                                 int ldo, int M, int N, int K, int relu) {
  __shared__ unsigned short As[64][72];
  __shared__ unsigned short Ws[64][72];
  const int tid = threadIdx.x;
  const int lane = tid & 63, wv = tid >> 6;
  const int wm = wv >> 1, wn = wv & 1;
  const int m0 = blockIdx.x * 64, n0 = blockIdx.y * 64;
  const int l15 = lane & 15, l4 = lane >> 4;

  f32x4 acc[2][2] = {};
  for (int k0 = 0; k0 < K; k0 += 64) {
#pragma unroll
    for (int t = 0; t < 2; ++t) {
      int u = t * 256 + tid;
      int r = u >> 3, c8 = u & 7;
      int ra = m0 + r; if (ra >= M) ra = M - 1;
      *(u16x8*)&As[r][c8 * 8] = *(const u16x8*)(A + (size_t)ra * K + k0 + c8 * 8);
      *(u16x8*)&Ws[r][c8 * 8] = *(const u16x8*)(W + (size_t)(n0 + r) * K + k0 + c8 * 8);
    }
    __syncthreads();
#pragma unroll
    for (int ks = 0; ks < 64; ks += 32) {
      bf16x8 af[2], wf[2];
#pragma unroll
      for (int fr = 0; fr < 2; ++fr)
        af[fr] = *(const bf16x8*)&As[wm * 32 + fr * 16 + l15][ks + l4 * 8];
#pragma unroll
      for (int fn = 0; fn < 2; ++fn)
        wf[fn] = *(const bf16x8*)&Ws[wn * 32 + fn * 16 + l15][ks + l4 * 8];
#pragma unroll
      for (int fr = 0; fr < 2; ++fr)
#pragma unroll
        for (int fn = 0; fn < 2; ++fn)
          acc[fr][fn] = __builtin_amdgcn_mfma_f32_16x16x32_bf16(
              af[fr], wf[fn], acc[fr][fn], 0, 0, 0);
    }
    __syncthreads();
  }
#pragma unroll
  for (int fr = 0; fr < 2; ++fr)
#pragma unroll
    for (int fn = 0; fn < 2; ++fn) {
      int col = n0 + wn * 32 + fn * 16 + l15;
      float bs = bias[col];
#pragma unroll
      for (int j = 0; j < 4; ++j) {
        int row = m0 + wm * 32 + fr * 16 + l4 * 4 + j;
        if (row >= M) continue;
        float v = acc[fr][fn][j] + bs;
        if (res) v += res[(size_t)row * ldo + col];
        if (relu) v = fmaxf(v, 0.f);
        if (outf) outf[(size_t)row * ldo + col] = v;
        if (outb) outb[(size_t)row * ldo + col] = f2b(v);
      }
    }
}

// ---------------------------------------------------------------- bf16 MFMA GEMM (value proj, 128x128)
__global__ __launch_bounds__(256) void gemm_vmfma_k(const unsigned short* __restrict__ A,
                                                    const unsigned short* __restrict__ W,
                                                    const float* __restrict__ bias,
                                                    unsigned short* __restrict__ C,
                                                    int M) {
  __shared__ unsigned short As[128][72];
  __shared__ unsigned short Ws[128][72];
  const int tid = threadIdx.x;
  const int lane = tid & 63, wv = tid >> 6;
  const int wm = wv >> 1, wn = wv & 1;
  const int m0 = blockIdx.x * 128, n0 = blockIdx.y * 128;
  const int l15 = lane & 15, l4 = lane >> 4;

  f32x4 acc[4][4] = {};

  for (int k0 = 0; k0 < 256; k0 += 64) {
#pragma unroll
    for (int t = 0; t < 4; ++t) {
      int u = t * 256 + tid;
      int r = u >> 3, c8 = u & 7;
      int ra = m0 + r; if (ra >= M) ra = M - 1;
      *(u16x8*)&As[r][c8 * 8] = *(const u16x8*)(A + (size_t)ra * 256 + k0 + c8 * 8);
      *(u16x8*)&Ws[r][c8 * 8] = *(const u16x8*)(W + (size_t)(n0 + r) * 256 + k0 + c8 * 8);
    }
    __syncthreads();
#pragma unroll
    for (int ks = 0; ks < 64; ks += 32) {
      bf16x8 af[4], bf[4];
#pragma unroll
      for (int fr = 0; fr < 4; ++fr)
        af[fr] = *(const bf16x8*)&As[wm * 64 + fr * 16 + l15][ks + l4 * 8];
#pragma unroll
      for (int fn = 0; fn < 4; ++fn)
        bf[fn] = *(const bf16x8*)&Ws[wn * 64 + fn * 16 + l15][ks + l4 * 8];
#pragma unroll
      for (int fr = 0; fr < 4; ++fr)
#pragma unroll
        for (int fn = 0; fn < 4; ++fn)
          acc[fr][fn] = __builtin_amdgcn_mfma_f32_16x16x32_bf16(
              af[fr], bf[fn], acc[fr][fn], 0, 0, 0);
    }
    __syncthreads();
  }
#pragma unroll
  for (int fr = 0; fr < 4; ++fr)
#pragma unroll
    for (int fn = 0; fn < 4; ++fn) {
      int col = n0 + wn * 64 + fn * 16 + l15;
      float bs = bias[col];
#pragma unroll
      for (int j = 0; j < 4; ++j) {
        int row = m0 + wm * 64 + fr * 16 + l4 * 4 + j;
        if (row < M) C[(size_t)row * 256 + col] = f2b(acc[fr][fn][j] + bs);
      }
    }
}

// ---------------------------------------------------------------- MFMA flash self-attn
__global__ __launch_bounds__(256) void fattn_mfma_k(const unsigned short* __restrict__ qkv,
                                                    unsigned short* __restrict__ o) {
  __shared__ unsigned short Qlds[64][40];
  __shared__ unsigned short Klds[64][40];
  __shared__ unsigned short Vt[32][72];   // V transposed [dh][key]
  __shared__ unsigned short Plds[64][72];
  const int tid = threadIdx.x;
  const int lane = tid & 63;
  const int wq = tid >> 6;
  const int l15 = lane & 15, l4 = lane >> 4;
  const int q0 = blockIdx.x * 64;
  const int h = blockIdx.y, b = blockIdx.z;
  const int hq = h * 32;
  const size_t rowb = (size_t)b * NQ;

  {
    int q = q0 + (tid >> 2);
    int qc = q < NQ ? q : NQ - 1;
    *(u16x8*)&Qlds[tid >> 2][(tid & 3) * 8] =
        *(const u16x8*)(qkv + (rowb + qc) * 768 + hq + (tid & 3) * 8);
  }
  __syncthreads();
  const bf16x8 qf = *(const bf16x8*)&Qlds[wq * 16 + l15][l4 * 8];

  float m_r[4] = {-1e30f, -1e30f, -1e30f, -1e30f};
  float l_r[4] = {0.f, 0.f, 0.f, 0.f};
  f32x4 oacc[2] = {};

  for (int k0 = 0; k0 < NQ; k0 += 64) {
    __syncthreads();
    {
      int kk = k0 + (tid >> 2);
      int kc = kk < NQ ? kk : NQ - 1;
      const unsigned short* kbase = qkv + (rowb + kc) * 768 + hq + (tid & 3) * 8;
      u16x8 kv = *(const u16x8*)(kbase + 256);
      u16x8 vv = *(const u16x8*)(kbase + 512);
      *(u16x8*)&Klds[tid >> 2][(tid & 3) * 8] = kv;
#pragma unroll
      for (int i = 0; i < 8; ++i) Vt[(tid & 3) * 8 + i][tid >> 2] = vv[i];
    }
    __syncthreads();

    f32x4 s[4];
#pragma unroll
    for (int fc = 0; fc < 4; ++fc) {
      bf16x8 kf = *(const bf16x8*)&Klds[fc * 16 + l15][l4 * 8];
      s[fc] = __builtin_amdgcn_mfma_f32_16x16x32_bf16(qf, kf, (f32x4){0.f, 0.f, 0.f, 0.f}, 0, 0, 0);
    }
#pragma unroll
    for (int fc = 0; fc < 4; ++fc) {
      bool oob = (k0 + fc * 16 + l15) >= NQ;
#pragma unroll
      for (int j = 0; j < 4; ++j)
        s[fc][j] = oob ? -1e30f : s[fc][j] * ATT_SCALE;
    }
#pragma unroll
    for (int j = 0; j < 4; ++j) {
      float tm = fmaxf(fmaxf(s[0][j], s[1][j]), fmaxf(s[2][j], s[3][j]));
      tm = fmaxf(tm, __shfl_xor(tm, 1, 16));
      tm = fmaxf(tm, __shfl_xor(tm, 2, 16));
      tm = fmaxf(tm, __shfl_xor(tm, 4, 16));
      tm = fmaxf(tm, __shfl_xor(tm, 8, 16));
      float mn = fmaxf(m_r[j], tm);
      float sf = __expf(m_r[j] - mn);
      m_r[j] = mn;
      oacc[0][j] *= sf;
      oacc[1][j] *= sf;
      float rs = 0.f;
#pragma unroll
      for (int fc = 0; fc < 4; ++fc) {
        float pv = __expf(s[fc][j] - mn);
        s[fc][j] = pv;
        rs += pv;
      }
      rs += __shfl_xor(rs, 1, 16);
      rs += __shfl_xor(rs, 2, 16);
      rs += __shfl_xor(rs, 4, 16);
      rs += __shfl_xor(rs, 8, 16);
      l_r[j] = l_r[j] * sf + rs;
    }
#pragma unroll
    for (int fc = 0; fc < 4; ++fc)
#pragma unroll
      for (int j = 0; j < 4; ++j)
        Plds[wq * 16 + l4 * 4 + j][fc * 16 + l15] = f2b(s[fc][j]);
    __syncthreads();
#pragma unroll
    for (int ks = 0; ks < 2; ++ks) {
      bf16x8 pf = *(const bf16x8*)&Plds[wq * 16 + l15][ks * 32 + l4 * 8];
#pragma unroll
      for (int oc = 0; oc < 2; ++oc) {
        bf16x8 vf = *(const bf16x8*)&Vt[oc * 16 + l15][ks * 32 + l4 * 8];
        oacc[oc] = __builtin_amdgcn_mfma_f32_16x16x32_bf16(pf, vf, oacc[oc], 0, 0, 0);
      }
    }
  }
#pragma unroll
  for (int j = 0; j < 4; ++j) {
    int q = q0 + wq * 16 + l4 * 4 + j;
    if (q < NQ) {
      float inv = 1.f / l_r[j];
      o[(rowb + q) * 256 + hq + l15] = f2b(oacc[0][j] * inv);
      o[(rowb + q) * 256 + hq + 16 + l15] = f2b(oacc[1][j] * inv);
    }
  }
}

// ---------------------------------------------------------------- MSDA sample
// 256 thr = 8 heads x 4 levels x 8 ch-slots; each thread: 4 points x 4 corners,
// u16x4 (4ch) loads; cross-level reduce via shfl_xor(8,16).
__global__ __launch_bounds__(256) void msda_k(const float* __restrict__ refp,
                                              const float* __restrict__ vr,
                                              const unsigned short* __restrict__ value,
                                              const float* __restrict__ cat,
                                              unsigned short* __restrict__ outp) {
  const int HW[4][2] = {{92, 160}, {46, 80}, {23, 40}, {12, 20}};
  const int START[4] = {0, 14720, 18400, 19320};
  const int qi = blockIdx.x, b = blockIdx.y;
  const int tid = threadIdx.x;
  const int h = tid >> 5;
  const int r = tid & 31;
  const int lvl = r >> 3;
  const int li = r & 7;
  const size_t base = (size_t)(b * NQ + qi);
  const float rx = refp[base * 3 + 0];
  const float rz = refp[base * 3 + 2];

  // softmax over this head's 16 logits (redundant x32, cheap f32x4 loads)
  const float* lg = cat + base * 384 + 256 + h * 16;
  float4 L0 = *(const float4*)(lg + 0);
  float4 L1 = *(const float4*)(lg + 4);
  float4 L2 = *(const float4*)(lg + 8);
  float4 L3 = *(const float4*)(lg + 12);
  float mx = fmaxf(fmaxf(fmaxf(L0.x, L0.y), fmaxf(L0.z, L0.w)),
                   fmaxf(fmaxf(fmaxf(L1.x, L1.y), fmaxf(L1.z, L1.w)),
                         fmaxf(fmaxf(fmaxf(L2.x, L2.y), fmaxf(L2.z, L2.w)),
                               fmaxf(fmaxf(L3.x, L3.y), fmaxf(L3.z, L3.w)))));
  float4 E0 = {__expf(L0.x - mx), __expf(L0.y - mx), __expf(L0.z - mx), __expf(L0.w - mx)};
  float4 E1 = {__expf(L1.x - mx), __expf(L1.y - mx), __expf(L1.z - mx), __expf(L1.w - mx)};
  float4 E2 = {__expf(L2.x - mx), __expf(L2.y - mx), __expf(L2.z - mx), __expf(L2.w - mx)};
  float4 E3 = {__expf(L3.x - mx), __expf(L3.y - mx), __expf(L3.z - mx), __expf(L3.w - mx)};
  float sum = E0.x + E0.y + E0.z + E0.w + E1.x + E1.y + E1.z + E1.w +
              E2.x + E2.y + E2.z + E2.w + E3.x + E3.y + E3.z + E3.w;
  const float inv = 1.f / sum;
  float4 Emy = lvl == 0 ? E0 : lvl == 1 ? E1 : lvl == 2 ? E2 : E3;
  float wl[4] = {Emy.x * inv, Emy.y * inv, Emy.z * inv, Emy.w * inv};

  const int H = HW[lvl][0], W = HW[lvl][1];
  const float refx = rx * vr[(b * LEVELS + lvl) * 2 + 0] * (float)W;
  const float refy = rz * vr[(b * LEVELS + lvl) * 2 + 1] * (float)H;
  const unsigned short* vbase = value + ((size_t)b * SLEN + START[lvl]) * DMODEL + h * DHEAD + li * 4;
  const float* ob = cat + base * 384 + h * 32 + lvl * 8;

  float a0 = 0.f, a1 = 0.f, a2 = 0.f, a3 = 0.f;
#pragma unroll
  for (int p = 0; p < 4; ++p) {
    const float x = refx + ob[p * 2 + 0] - 0.5f;
    const float y = refy + ob[p * 2 + 1] - 0.5f;
    const float x0f = floorf(x), y0f = floorf(y);
    const float fx = x - x0f, fy = y - y0f;
    const int x0 = (int)x0f, y0 = (int)y0f;
#pragma unroll
    for (int ci = 0; ci < 4; ++ci) {
      const int xi = x0 + (ci & 1);
      const int yi = y0 + (ci >> 1);
      if ((xi >= 0) && (xi < W) && (yi >= 0) && (yi < H)) {
        const float wxy = ((ci & 1) ? fx : 1.f - fx) * ((ci >> 1) ? fy : 1.f - fy) * wl[p];
        u16x4 v4 = *(const u16x4*)(vbase + (size_t)(yi * W + xi) * DMODEL);
        a0 = fmaf(wxy, b2f(v4[0]), a0);
        a1 = fmaf(wxy, b2f(v4[1]), a1);
        a2 = fmaf(wxy, b2f(v4[2]), a2);
        a3 = fmaf(wxy, b2f(v4[3]), a3);
      }
    }
  }
  // reduce across the 4 levels (lane bits 3,4)
  a0 += __shfl_xor(a0, 8);  a1 += __shfl_xor(a1, 8);
  a2 += __shfl_xor(a2, 8);  a3 += __shfl_xor(a3, 8);
  a0 += __shfl_xor(a0, 16); a1 += __shfl_xor(a1, 16);
  a2 += __shfl_xor(a2, 16); a3 += __shfl_xor(a3, 16);
  if (lvl == 0) {
    u16x4 o4 = {f2b(a0), f2b(a1), f2b(a2), f2b(a3)};
    *(u16x4*)(outp + base * 256 + h * 32 + li * 4) = o4;
  }
}

// ---------------------------------------------------------------- LayerNorm: wave per row, 4 rows/block
__global__ __launch_bounds__(256) void ln_k(const float* __restrict__ src,
                                            const float* __restrict__ w,
                                            const float* __restrict__ bias,
                                            const float* __restrict__ qpos,
                                            float* __restrict__ dst,
                                            unsigned short* __restrict__ dstb,
                                            unsigned short* __restrict__ qposb) {
  const int row = blockIdx.x * 4 + (threadIdx.x >> 6);
  const int lane = threadIdx.x & 63;
  const size_t o = (size_t)row * DMODEL + lane * 4;
  float4 x = *(const float4*)(src + o);
  float s = x.x + x.y + x.z + x.w;
#pragma unroll
  for (int m = 1; m < 64; m <<= 1) s += __shfl_xor(s, m);
  const float mu = s * (1.f / DMODEL);
  float4 v = {x.x - mu, x.y - mu, x.z - mu, x.w - mu};
  float q = v.x * v.x + v.y * v.y + v.z * v.z + v.w * v.w;
#pragma unroll
  for (int m = 1; m < 64; m <<= 1) q += __shfl_xor(q, m);
  const float rstd = rsqrtf(q * (1.f / DMODEL) + EPS_LN);
  float4 wv = *(const float4*)(w + lane * 4);
  float4 bv = *(const float4*)(bias + lane * 4);
  float4 y = {v.x * rstd * wv.x + bv.x, v.y * rstd * wv.y + bv.y,
              v.z * rstd * wv.z + bv.z, v.w * rstd * wv.w + bv.w};
  *(float4*)(dst + o) = y;
  if (dstb) {
    u16x4 ob = {f2b(y.x), f2b(y.y), f2b(y.z), f2b(y.w)};
    *(u16x4*)(dstb + o) = ob;
  }
  if (qposb) {
    float4 qv = *(const float4*)(qpos + o);
    u16x4 ob = {f2b(y.x + qv.x), f2b(y.y + qv.y), f2b(y.z + qv.z), f2b(y.w + qv.w)};
    *(u16x4*)(qposb + o) = ob;
  }
}

// ---------------------------------------------------------------- launcher
extern "C" void kernel_launch(void* const* d_in, const int* in_sizes, int n_in,
                              void* d_out, int out_size, void* d_ws, size_t ws_size,
                              hipStream_t stream) {
  const float* tgt     = (const float*)d_in[0];
  const float* refp    = (const float*)d_in[1];
  const float* src     = (const float*)d_in[2];
  const float* vr      = (const float*)d_in[3];
  const float* qpos    = (const float*)d_in[4];
  const float* sa_in_w = (const float*)d_in[5];
  const float* sa_in_b = (const float*)d_in[6];
  const float* sa_out_w= (const float*)d_in[7];
  const float* sa_out_b= (const float*)d_in[8];
  const float* samp_w  = (const float*)d_in[9];
  const float* samp_b  = (const float*)d_in[10];
  const float* attn_w  = (const float*)d_in[11];
  const float* attn_b  = (const float*)d_in[12];
  const float* val_w   = (const float*)d_in[13];
  const float* val_b   = (const float*)d_in[14];
  const float* ca_out_w= (const float*)d_in[15];
  const float* ca_out_b= (const float*)d_in[16];
  const float* ffn1_w  = (const float*)d_in[17];
  const float* ffn1_b  = (const float*)d_in[18];
  const float* ffn2_w  = (const float*)d_in[19];
  const float* ffn2_b  = (const float*)d_in[20];
  const float* ln1_w   = (const float*)d_in[21];
  const float* ln1_b   = (const float*)d_in[22];
  const float* ln2_w   = (const float*)d_in[23];
  const float* ln2_b   = (const float*)d_in[24];
  const float* ln3_w   = (const float*)d_in[25];
  const float* ln3_b   = (const float*)d_in[26];

  const int M = BS * NQ;                 // 3600
  const int MV = BS * SLEN;              // 78240
  const size_t TOK = (size_t)M * DMODEL; // 921600

  float* ws = (float*)d_ws;
  size_t off = 0;
  auto alloc = [&](size_t n) { float* p = ws + off; off += n; return p; };
  auto allocb = [&](size_t n) { unsigned short* p = (unsigned short*)(ws + off); off += (n + 1) / 2; return p; };
  float* cur    = alloc(TOK);
  float* tmp    = alloc(TOK);
  float* catout = alloc((size_t)M * 384);
  float* b_cacat= alloc((size_t)NLAYERS * 384);
  unsigned short* cur_bf  = allocb(TOK);
  unsigned short* qbuf_bf = allocb(TOK);
  unsigned short* sao_bf  = allocb(TOK);
  unsigned short* msda_bf = allocb(TOK);
  unsigned short* qkv_bf  = allocb((size_t)M * 768);
  unsigned short* ffnh_bf = allocb((size_t)M * DFF);
  unsigned short* src_bf  = allocb((size_t)MV * DMODEL);
  unsigned short* value_bf= allocb((size_t)MV * DMODEL);
  unsigned short* w_in_bf   = allocb((size_t)NLAYERS * 768 * 256);
  unsigned short* w_saout_bf= allocb((size_t)NLAYERS * 256 * 256);
  unsigned short* w_cacat_bf= allocb((size_t)NLAYERS * 384 * 256);
  unsigned short* w_val_bf  = allocb((size_t)NLAYERS * 256 * 256);
  unsigned short* w_caout_bf= allocb((size_t)NLAYERS * 256 * 256);
  unsigned short* w_ffn1_bf = allocb((size_t)NLAYERS * DFF * 256);
  unsigned short* w_ffn2_bf = allocb((size_t)NLAYERS * 256 * DFF);

  const int n4 = (int)(TOK / 4);
  const dim3 blk(256);
  const dim3 gE((n4 + 255) / 256);

  copycvt_k<<<gE, blk, 0, stream>>>(tgt, qpos, cur, cur_bf, qbuf_bf, n4);
  f2ball_k<<<dim3(2048), blk, 0, stream>>>(src, sa_in_w, sa_out_w, val_w, ca_out_w,
                                           ffn1_w, ffn2_w,
                                           src_bf, w_in_bf, w_saout_bf, w_val_bf,
                                           w_caout_bf, w_ffn1_bf, w_ffn2_bf);
  catw_k<<<dim3(576), blk, 0, stream>>>(samp_w, attn_w, samp_b, attn_b, w_cacat_bf, b_cacat);

  const dim3 gQK((M + 63) / 64, 512 / 64);
  const dim3 gV((M + 63) / 64, 256 / 64);
  const dim3 gN256((M + 63) / 64, 256 / 64);
  const dim3 gCat((M + 63) / 64, 384 / 64);
  const dim3 gF1((M + 63) / 64, DFF / 64);
  const dim3 gLN(M / 4);

  for (int l = 0; l < NLAYERS; ++l) {
    const unsigned short* wq = w_in_bf + (size_t)l * 768 * 256;
    const float* bq = sa_in_b + (size_t)l * 768;

    gemm_bf_k<<<gQK, blk, 0, stream>>>(qbuf_bf, wq, bq, nullptr,
                                       nullptr, qkv_bf, 768, M, 512, 256, 0);
    gemm_bf_k<<<gV, blk, 0, stream>>>(cur_bf, wq + 512 * 256, bq + 512, nullptr,
                                      nullptr, qkv_bf + 512, 768, M, 256, 256, 0);

    fattn_mfma_k<<<dim3((NQ + 63) / 64, HEADS, BS), blk, 0, stream>>>(qkv_bf, sao_bf);

    gemm_bf_k<<<gN256, blk, 0, stream>>>(sao_bf, w_saout_bf + (size_t)l * 256 * 256,
                                         sa_out_b + l * 256, cur, tmp, nullptr, 256, M, 256, 256, 0);
    ln_k<<<gLN, blk, 0, stream>>>(tmp, ln1_w + l * 256, ln1_b + l * 256, qpos,
                                  cur, nullptr, qbuf_bf);

    // cross-attn (MSDA)
    gemm_vmfma_k<<<dim3((MV + 127) / 128, 2), blk, 0, stream>>>(
        src_bf, w_val_bf + (size_t)l * 256 * 256, val_b + l * 256, value_bf, MV);
    gemm_bf_k<<<gCat, blk, 0, stream>>>(qbuf_bf, w_cacat_bf + (size_t)l * 384 * 256,
                                        b_cacat + l * 384, nullptr, catout, nullptr, 384, M, 384, 256, 0);

    msda_k<<<dim3(NQ, BS), blk, 0, stream>>>(refp, vr, value_bf, catout, msda_bf);

    gemm_bf_k<<<gN256, blk, 0, stream>>>(msda_bf, w_caout_bf + (size_t)l * 256 * 256,
                                         ca_out_b + l * 256, cur, tmp, nullptr, 256, M, 256, 256, 0);
    ln_k<<<gLN, blk, 0, stream>>>(tmp, ln2_w + l * 256, ln2_b + l * 256, nullptr,
                                  cur, cur_bf, nullptr);

    // FFN
    gemm_bf_k<<<gF1, blk, 0, stream>>>(cur_bf, w_ffn1_bf + (size_t)l * DFF * 256,
                                       ffn1_b + l * DFF, nullptr, nullptr, ffnh_bf, DFF, M, DFF, 256, 1);
    gemm_bf_k<<<gN256, blk, 0, stream>>>(ffnh_bf, w_ffn2_bf + (size_t)l * 256 * DFF,
                                         ffn2_b + l * 256, cur, tmp, nullptr, 256, M, 256, DFF, 0);
    const bool last = (l == NLAYERS - 1);
    ln_k<<<gLN, blk, 0, stream>>>(tmp, ln3_w + l * 256, ln3_b + l * 256,
                                  last ? nullptr : qpos,
                                  last ? (float*)d_out : cur,
                                  last ? nullptr : cur_bf,
                                  last ? nullptr : qbuf_bf);
  }
}